// Round 1
// 822.860 us; speedup vs baseline: 1.1001x; 1.1001x over previous
//
#include <hip/hip_runtime.h>
#include <hip/hip_bf16.h>

#define GN 50000
#define GE 800000
#define GH 4
#define GFH 32
#define GC 40
#define GIN 128

typedef __hip_bfloat16 bf16;
typedef __attribute__((ext_vector_type(8))) short bf16x8;
typedef __attribute__((ext_vector_type(4))) float f32x4;

// mode m: 0 = tensor stored as bf16, 1 = stored as fp32
static __device__ __forceinline__ float ldx(const void* p, size_t i, int m) {
    if (m) return ((const float*)p)[i];
    return __bfloat162float(((const bf16*)p)[i]);
}
static __device__ __forceinline__ void stx(void* p, size_t i, int m, float v) {
    if (m) ((float*)p)[i] = v;
    else ((bf16*)p)[i] = __float2bfloat16(v);
}
static __device__ __forceinline__ unsigned short f2bfu(float v) {
    union { bf16 b; unsigned short u; } cv;
    cv.b = __float2bfloat16(v);
    return cv.u;
}
static __device__ __forceinline__ float lo16(unsigned u) { return __uint_as_float(u << 16); }
static __device__ __forceinline__ float hi16(unsigned u) { return __uint_as_float(u & 0xFFFF0000u); }
static __device__ __forceinline__ float guard_finite(float v) {
    if (!(v == v) || fabsf(v) > 1e30f) return 0.f;
    return v;
}

// ---------------- dtype probe: fp32 misread as bf16 shows wild exponents ----------------
__global__ void detect_kernel(const unsigned short* __restrict__ f, int* __restrict__ flag) {
    int t = threadIdx.x;  // 256
    unsigned short u = f[t];
    int e = (u >> 7) & 0xFF;
    if (e >= 0x8E) atomicAdd(flag, 1);  // |val| >= 2^15 or inf/nan -> not sane bf16 data
}

__global__ void sentinel_kernel(unsigned short* __restrict__ o, int n) {
    int i = blockIdx.x * blockDim.x + threadIdx.x;
    if (i < n) o[i] = 0x3F80;  // bf16 1.0
}

// ---------------- CSR build ----------------
__global__ void count_kernel(const int* __restrict__ dst, int* __restrict__ deg, int n) {
    int e = blockIdx.x * blockDim.x + threadIdx.x;
    if (e < n) {
        int d = dst[e];
        if (d >= 0 && d < GN) atomicAdd(&deg[d], 1);
    }
}

// ---- 3-pass device-wide scan (replaces the 90us single-block serial scan) ----
// Pass 1: per-block (256 elems) inclusive scan -> tmp (staged in cursor); block totals -> bsum
__global__ void scan1_kernel(const int* __restrict__ deg, int* __restrict__ tmp,
                             int* __restrict__ bsum, int n) {
    int tid = threadIdx.x;
    int i = blockIdx.x * 256 + tid;
    int v = (i < n) ? deg[i] : 0;
    int lane = tid & 63, wid = tid >> 6;
    int s = v;
#pragma unroll
    for (int off = 1; off < 64; off <<= 1) {
        int u = __shfl_up(s, off);
        if (lane >= off) s += u;
    }
    __shared__ int wsum[4];
    if (lane == 63) wsum[wid] = s;
    __syncthreads();
    int woff = 0;
#pragma unroll
    for (int w = 0; w < 4; w++) woff += (w < wid) ? wsum[w] : 0;
    int incl = s + woff;
    if (i < n) tmp[i] = incl;
    if (tid == 255) bsum[blockIdx.x] = incl;  // block total (zeros padded past n)
}

// Pass 2: single block scans block totals (nb <= 256) to EXCLUSIVE offsets, in place
__global__ void scan2_kernel(int* __restrict__ bsum, int nb) {
    int tid = threadIdx.x;
    int v = (tid < nb) ? bsum[tid] : 0;
    int lane = tid & 63, wid = tid >> 6;
    int s = v;
#pragma unroll
    for (int off = 1; off < 64; off <<= 1) {
        int u = __shfl_up(s, off);
        if (lane >= off) s += u;
    }
    __shared__ int wsum[4];
    if (lane == 63) wsum[wid] = s;
    __syncthreads();
    int woff = 0;
#pragma unroll
    for (int w = 0; w < 4; w++) woff += (w < wid) ? wsum[w] : 0;
    if (tid < nb) bsum[tid] = s + woff - v;  // exclusive
}

// Pass 3: add block offset; emit indptr[i+1] and cursor[i] (tmp may alias cursor)
__global__ void scan3_kernel(const int* __restrict__ deg, const int* __restrict__ tmp,
                             const int* __restrict__ bsum, int* __restrict__ indptr,
                             int* __restrict__ cursor, int n) {
    int i = blockIdx.x * 256 + threadIdx.x;
    if (i < n) {
        int incl = tmp[i] + bsum[blockIdx.x];
        indptr[i + 1] = incl;
        cursor[i] = incl - deg[i];
        if (i == 0) indptr[0] = 0;
    }
}

__global__ void scatter_kernel(const int* __restrict__ src, const int* __restrict__ dst,
                               int* __restrict__ cursor, int* __restrict__ csr_src, int n) {
    int e = blockIdx.x * blockDim.x + threadIdx.x;
    if (e < n) {
        int d = dst[e];
        if (d < 0 || d >= GN) return;
        int p = atomicAdd(&cursor[d], 1);
        if (p >= 0 && p < GE) csr_src[p] = src[e];
    }
}

// ---------------- w-mean: wmt[c][128] (c<48, zero-pad c>=40) = mean_h w_lin2[k][h*40+c] ----------------
__global__ void wmean_kernel(const void* __restrict__ w, unsigned short* __restrict__ wmt,
                             const int* __restrict__ flag) {
    int m = (*flag != 0) ? 1 : 0;
    int idx = blockIdx.x * blockDim.x + threadIdx.x;
    if (idx < 48 * 128) {
        int c = idx >> 7, k = idx & 127;
        float s = 0.f;
        if (c < 40) {
            s = 0.25f * (ldx(w, (size_t)k * 160 + c, m) + ldx(w, (size_t)k * 160 + 40 + c, m) +
                         ldx(w, (size_t)k * 160 + 80 + c, m) + ldx(w, (size_t)k * 160 + 120 + c, m));
        }
        wmt[c * 128 + k] = f2bfu(s);
    }
}

// ---------------- MFMA GEMM: Y[N,M](bf16) = X[N,128] @ W[128,M] ----------------
__global__ __launch_bounds__(256) void gemm_tile(const void* __restrict__ X, int xext,
                                                 const void* __restrict__ W,
                                                 bf16* __restrict__ Y, int nrows, int M,
                                                 const int* __restrict__ flag) {
    constexpr int LDX = 136;  // bf16 units; pad 8 -> 2-way LDS conflict only (free)
    __shared__ unsigned short Xs[64 * LDX];  // [r][k]
    __shared__ unsigned short Wt[64 * LDX];  // [c][k]
    int m = (*flag != 0) ? 1 : 0;
    int mx_ = xext ? m : 0;
    int tid = threadIdx.x;
    int rb = blockIdx.x * 64, cb = blockIdx.y * 64;

    for (int idx = tid; idx < 64 * 128; idx += 256) {
        int r = idx >> 7, k = idx & 127;
        int row = rb + r;
        Xs[r * LDX + k] =
            (row < nrows) ? f2bfu(ldx(X, (size_t)row * 128 + k, mx_)) : (unsigned short)0;
    }
    for (int idx = tid; idx < 128 * 64; idx += 256) {
        int k = idx >> 6, c = idx & 63;
        int col = cb + c;
        Wt[c * LDX + k] = (col < M) ? f2bfu(ldx(W, (size_t)k * M + col, m)) : (unsigned short)0;
    }
    __syncthreads();

    int wave = tid >> 6, lane = tid & 63;
    int lr = lane & 15, quad = lane >> 4;
    int mrow = wave * 16 + lr;

    f32x4 acc[4] = {};
    for (int kk = 0; kk < 128; kk += 32) {
        bf16x8 a = *(const bf16x8*)&Xs[mrow * LDX + kk + quad * 8];
#pragma unroll
        for (int nt = 0; nt < 4; nt++) {
            bf16x8 b = *(const bf16x8*)&Wt[(nt * 16 + lr) * LDX + kk + quad * 8];
            acc[nt] = __builtin_amdgcn_mfma_f32_16x16x32_bf16(a, b, acc[nt], 0, 0, 0);
        }
    }

    int drow = rb + wave * 16 + quad * 4;
#pragma unroll
    for (int nt = 0; nt < 4; nt++) {
        int col = cb + nt * 16 + lr;
#pragma unroll
        for (int i = 0; i < 4; i++) {
            int row = drow + i;
            if (row < nrows && col < M) Y[(size_t)row * M + col] = __float2bfloat16(acc[nt][i]);
        }
    }
}

// ---------------- MFMA in-place GEMM: X[nrows,128] <- X @ W[128,128] ----------------
__global__ __launch_bounds__(256) void gemm_inplace(bf16* __restrict__ X,
                                                    const void* __restrict__ W, int nrows,
                                                    const int* __restrict__ flag) {
    constexpr int LDX = 136;
    __shared__ unsigned short Xs[64 * LDX];    // [r][k]
    __shared__ unsigned short Wt[128 * LDX];   // [c][k]
    int m = (*flag != 0) ? 1 : 0;
    int tid = threadIdx.x;
    int rb = blockIdx.x * 64;

    for (int idx = tid; idx < 64 * 128; idx += 256) {
        int r = idx >> 7, k = idx & 127;
        int row = rb + r;
        Xs[r * LDX + k] =
            (row < nrows) ? ((const unsigned short*)X)[(size_t)row * 128 + k] : (unsigned short)0;
    }
    for (int idx = tid; idx < 128 * 128; idx += 256) {
        int k = idx >> 7, c = idx & 127;
        Wt[c * LDX + k] = f2bfu(ldx(W, (size_t)k * 128 + c, m));
    }
    __syncthreads();

    int wave = tid >> 6, lane = tid & 63;
    int lr = lane & 15, quad = lane >> 4;
    int mrow = wave * 16 + lr;

    f32x4 acc[8] = {};
    for (int kk = 0; kk < 128; kk += 32) {
        bf16x8 a = *(const bf16x8*)&Xs[mrow * LDX + kk + quad * 8];
#pragma unroll
        for (int nt = 0; nt < 8; nt++) {
            bf16x8 b = *(const bf16x8*)&Wt[(nt * 16 + lr) * LDX + kk + quad * 8];
            acc[nt] = __builtin_amdgcn_mfma_f32_16x16x32_bf16(a, b, acc[nt], 0, 0, 0);
        }
    }

    int drow = rb + wave * 16 + quad * 4;
#pragma unroll
    for (int nt = 0; nt < 8; nt++) {
        int col = nt * 16 + lr;
#pragma unroll
        for (int i = 0; i < 4; i++) {
            int row = drow + i;
            if (row < nrows) X[(size_t)row * 128 + col] = __float2bfloat16(acc[nt][i]);
        }
    }
}

// ---------------- skipmean in-place: X[:,0:40] <- X @ wmt^T (wmt: [48][128]) ----------------
// Row-exclusive blocks: stage own 64 rows (full 128 wide) to LDS first, then overwrite cols<40.
__global__ __launch_bounds__(256) void skipmean_inplace(bf16* __restrict__ X,
                                                        const unsigned short* __restrict__ wmt,
                                                        int nrows) {
    constexpr int LDX = 136;
    __shared__ unsigned short Xs[64 * LDX];  // [r][k]
    __shared__ unsigned short Wt[48 * LDX];  // [c][k]
    int tid = threadIdx.x;
    int rb = blockIdx.x * 64;

    for (int idx = tid; idx < 64 * 128; idx += 256) {
        int r = idx >> 7, k = idx & 127;
        int row = rb + r;
        Xs[r * LDX + k] =
            (row < nrows) ? ((const unsigned short*)X)[(size_t)row * 128 + k] : (unsigned short)0;
    }
    for (int idx = tid; idx < 48 * 128; idx += 256) {
        int c = idx >> 7, k = idx & 127;
        Wt[c * LDX + k] = wmt[c * 128 + k];
    }
    __syncthreads();

    int wave = tid >> 6, lane = tid & 63;
    int lr = lane & 15, quad = lane >> 4;
    int mrow = wave * 16 + lr;

    f32x4 acc[3] = {};
    for (int kk = 0; kk < 128; kk += 32) {
        bf16x8 a = *(const bf16x8*)&Xs[mrow * LDX + kk + quad * 8];
#pragma unroll
        for (int nt = 0; nt < 3; nt++) {
            bf16x8 b = *(const bf16x8*)&Wt[(nt * 16 + lr) * LDX + kk + quad * 8];
            acc[nt] = __builtin_amdgcn_mfma_f32_16x16x32_bf16(a, b, acc[nt], 0, 0, 0);
        }
    }

    int drow = rb + wave * 16 + quad * 4;
#pragma unroll
    for (int nt = 0; nt < 3; nt++) {
        int col = nt * 16 + lr;
        if (col < 40) {
#pragma unroll
            for (int i = 0; i < 4; i++) {
                int row = drow + i;
                if (row < nrows) X[(size_t)row * 128 + col] = __float2bfloat16(acc[nt][i]);
            }
        }
    }
}

// ---------------- el/er: [N,H] dot over F ----------------
__global__ void elr_kernel(const bf16* __restrict__ ft, const void* __restrict__ al,
                           const void* __restrict__ ar, float* __restrict__ el,
                           float* __restrict__ er, int n, int F, const int* __restrict__ flag) {
    int m = (*flag != 0) ? 1 : 0;
    int gid = blockIdx.x * blockDim.x + threadIdx.x;
    if (gid >= n * 4) return;
    int nid = gid >> 2, h = gid & 3;
    const bf16* f = ft + (size_t)nid * (4 * F) + h * F;
    float sl = 0.f, sr = 0.f;
    for (int i = 0; i < F; i++) {
        float v = __bfloat162float(f[i]);
        sl += v * ldx(al, h * F + i, m);
        sr += v * ldx(ar, h * F + i, m);
    }
    el[gid] = sl;
    er[gid] = sr;
}

// ---------------- per-dst softmax + aggregation ----------------
// r12 gather structure (feature-pair + edge-parity); shuffle-based s reduction (1 barrier);
// non-FINAL: skip precomputed in skip_pre (pair read).  FINAL: head-averaged skip precomputed
// into h_in[:,0:40] by skipmean_inplace; added in the epilogue.
// out may alias skip_pre buffer: block v reads only row v, writes row v last.
template <int FTOT, bool FINAL>
__global__ __launch_bounds__(FINAL ? 192 : 128) void agg_kernel(
    const bf16* __restrict__ ft, const float* __restrict__ el, const float* __restrict__ er,
    const int* __restrict__ indptr, const int* __restrict__ csr_src,
    const void* __restrict__ bias, const void* __restrict__ h_in,
    const bf16* __restrict__ skip_pre, bf16* __restrict__ out,
    const void* __restrict__ bias_last, void* __restrict__ fout,
    const int* __restrict__ flag) {
    constexpr int CH = 128;
    constexpr int NT = FINAL ? 192 : 128;
    constexpr int FP = FTOT / 2;  // feature pairs
    constexpr int HF = FTOT / 4;  // head size
    int m = (*flag != 0) ? 1 : 0;
    int v = blockIdx.x;
    int t = threadIdx.x;
    int beg = indptr[v], end = indptr[v + 1];
    beg = max(0, min(beg, GE));
    end = max(beg, min(end, GE));

    __shared__ float wbuf[CH * 4];  // per-edge weights (4 heads); reused as merge buffer
    __shared__ int ubuf[CH];
    __shared__ float red[8];
    __shared__ float ovals[FINAL ? 160 : 1];
    __shared__ float lsm[FINAL ? 64 : 1];

    int g = (t < FTOT) ? (t / FP) : 0;
    int f = (t < FTOT) ? (t - g * FP) : 0;
    int c0 = 2 * f;
    int h0 = c0 / HF;

    float sk = 0.f, sk1_pre = 0.f;
    if (!FINAL && t < FP) {
        unsigned pk = *(const unsigned*)(skip_pre + (size_t)v * FTOT + c0);
        sk = lo16(pk);
        sk1_pre = hi16(pk);
    }

    int h = t & 3, slot = t >> 2;
    float erv = er[v * 4 + h];
    float s_part = 0.f;
    float a0 = 0.f, a1 = 0.f;

    for (int cb = beg; cb < end; cb += CH) {
        int chn = min(CH, end - cb);
        int chn_pad = (chn + 7) & ~7;
        if (t < 128) {
            for (int j = slot; j < chn; j += 32) {
                int u = csr_src[cb + j];
                u = min(max(u, 0), GN - 1);
                if (h == 0) ubuf[j] = u;
                float e = el[u * 4 + h] + erv;
                e = e > 0.f ? e : 0.2f * e;
                float w = __expf(fminf(e, 60.f));
                wbuf[j * 4 + h] = w;
                s_part += w;
            }
        }
        for (int j = chn + t; j < chn_pad; j += NT) {
            ubuf[j] = 0;
            wbuf[j * 4 + 0] = 0.f;
            wbuf[j * 4 + 1] = 0.f;
            wbuf[j * 4 + 2] = 0.f;
            wbuf[j * 4 + 3] = 0.f;
        }
        __syncthreads();
        if (t < FTOT) {
            for (int j = g; j < chn_pad; j += 8) {
                float w0 = wbuf[j * 4 + h0], w1 = wbuf[(j + 2) * 4 + h0];
                float w2 = wbuf[(j + 4) * 4 + h0], w3 = wbuf[(j + 6) * 4 + h0];
                int u0 = ubuf[j], u1 = ubuf[j + 2], u2 = ubuf[j + 4], u3 = ubuf[j + 6];
                unsigned p0 = *(const unsigned*)(ft + (size_t)u0 * FTOT + c0);
                unsigned p1 = *(const unsigned*)(ft + (size_t)u1 * FTOT + c0);
                unsigned p2 = *(const unsigned*)(ft + (size_t)u2 * FTOT + c0);
                unsigned p3 = *(const unsigned*)(ft + (size_t)u3 * FTOT + c0);
                a0 += w0 * lo16(p0) + w1 * lo16(p1) + w2 * lo16(p2) + w3 * lo16(p3);
                a1 += w0 * hi16(p0) + w1 * hi16(p1) + w2 * hi16(p2) + w3 * hi16(p3);
            }
        }
        __syncthreads();
    }

    // per-wave butterfly over slot bits (head preserved in lane&3), 1 barrier total
    if (t < 128) {
#pragma unroll
        for (int off = 4; off < 64; off <<= 1) s_part += __shfl_xor(s_part, off);
        if ((t & 63) < 4) red[((t >> 6) << 2) | (t & 3)] = s_part;
    }
    if (t < FTOT && g == 1) {
        wbuf[c0] = a0;
        wbuf[c0 + 1] = a1;
    }
    __syncthreads();

    if (t < FP) {
        float s0 = red[h0] + red[4 + h0];
        float acc0 = a0 + wbuf[c0];
        float acc1 = a1 + wbuf[c0 + 1];
        float r0 = (s0 > 0.f) ? acc0 / s0 : 0.f;
        float r1 = (s0 > 0.f) ? acc1 / s0 : 0.f;
        float o0 = r0 + ldx(bias, c0, m) + sk;
        float o1 = r1 + ldx(bias, c0 + 1, m) + sk1_pre;
        if constexpr (!FINAL) {
            unsigned pk = ((unsigned)f2bfu(guard_finite(o1)) << 16) |
                          (unsigned)f2bfu(guard_finite(o0));
            *(unsigned*)(out + (size_t)v * FTOT + c0) = pk;
        } else {
            ovals[c0] = o0;
            ovals[c0 + 1] = o1;
        }
    }

    if constexpr (FINAL) {
        __syncthreads();
        if (t < 40) {
            float sm = ldx(h_in, (size_t)v * 128 + t, 0);  // head-averaged skip (bf16)
            lsm[t] = 0.25f * (ovals[t] + ovals[40 + t] + ovals[80 + t] + ovals[120 + t]) + sm +
                     ldx(bias_last, t, m);
        }
        __syncthreads();
        if (t < 64) {
            float x = (t < 40) ? lsm[t] : -3.0e38f;
            float mx = x;
            for (int off = 1; off < 64; off <<= 1) mx = fmaxf(mx, __shfl_xor(mx, off));
            float ex = (t < 40) ? __expf(x - mx) : 0.f;
            float sum = ex;
            for (int off = 1; off < 64; off <<= 1) sum += __shfl_xor(sum, off);
            if (t < 40) stx(fout, (size_t)v * 40 + t, m, guard_finite(x - mx - __logf(sum)));
        }
    }
}

// ---------------- BatchNorm (+ ReLU) on bf16 [N,128] ----------------
__global__ void bn_stats(const bf16* __restrict__ x, float* __restrict__ gsum,
                         float* __restrict__ gsq, int n) {
    int c = threadIdx.x;  // 128
    int rows_per_block = (n + gridDim.x - 1) / gridDim.x;
    int r0 = blockIdx.x * rows_per_block;
    int r1 = min(n, r0 + rows_per_block);
    float s = 0.f, q = 0.f;
    for (int r = r0; r < r1; r++) {
        float v = __bfloat162float(x[(size_t)r * 128 + c]);
        s += v;
        q += v * v;
    }
    atomicAdd(&gsum[c], s);
    atomicAdd(&gsq[c], q);
}

__global__ void bn_apply(bf16* __restrict__ x, const float* __restrict__ gsum,
                         const float* __restrict__ gsq, const void* __restrict__ g,
                         const void* __restrict__ be, int n, const int* __restrict__ flag) {
    int m = (*flag != 0) ? 1 : 0;
    int gid = blockIdx.x * blockDim.x + threadIdx.x;
    if (gid >= n * 128) return;
    int c = gid & 127;
    float inv_n = 1.f / (float)n;
    float mu = gsum[c] * inv_n;
    float var = gsq[c] * inv_n - mu * mu;
    float y = (__bfloat162float(x[gid]) - mu) * rsqrtf(fmaxf(var, 0.f) + 1e-5f) * ldx(g, c, m) +
              ldx(be, c, m);
    x[gid] = __float2bfloat16(y > 0.f ? y : 0.f);
}

extern "C" void kernel_launch(void* const* d_in, const int* in_sizes, int n_in,
                              void* d_out, int out_size, void* d_ws, size_t ws_size,
                              hipStream_t stream) {
    const void* feat = d_in[0];
    const int* src = (const int*)d_in[1];
    const int* dst = (const int*)d_in[2];
    const void* w_fc0 = d_in[3];
    const void* al0 = d_in[4];
    const void* ar0 = d_in[5];
    const void* b0 = d_in[6];
    const void* w_lin0 = d_in[7];
    const void* g0 = d_in[8];
    const void* be0 = d_in[9];
    const void* w_fc1 = d_in[10];
    const void* al1 = d_in[11];
    const void* ar1 = d_in[12];
    const void* b1 = d_in[13];
    const void* w_lin1 = d_in[14];
    const void* g1 = d_in[15];
    const void* be1 = d_in[16];
    const void* w_fc2 = d_in[17];
    const void* al2 = d_in[18];
    const void* ar2 = d_in[19];
    const void* b2 = d_in[20];
    const void* w_lin2 = d_in[21];
    const void* bias_last = d_in[22];

    // ---- workspace guard: total need ~34.5 MB ----
    if (ws_size < 35000000) {
        sentinel_kernel<<<(out_size + 255) / 256, 256, 0, stream>>>((unsigned short*)d_out,
                                                                    out_size);
        return;
    }

    char* p = (char*)d_ws;
    auto alloc = [&](size_t bytes) {
        char* r = p;
        p += (bytes + 255) & ~(size_t)255;
        return r;
    };
    bf16* ftb = (bf16*)alloc((size_t)GN * 160 * 2);   // 16.0 MB
    bf16* hbuf = (bf16*)alloc((size_t)GN * 128 * 2);  // 12.8 MB
    float* elb = (float*)alloc((size_t)GN * 4 * 4);   // 0.8 MB
    float* erb = (float*)alloc((size_t)GN * 4 * 4);   // 0.8 MB
    int* indptr = (int*)alloc((size_t)(GN + 1) * 4);
    int* cursor = (int*)alloc((size_t)GN * 4);
    int* bsum = (int*)alloc(256 * 4);                 // block sums for 3-pass scan
    unsigned short* wmt = (unsigned short*)alloc(48 * 128 * 2);  // 12.3 KB
    char* zbase = p;  // ---- zero-initialized region ----
    int* deg = (int*)alloc((size_t)GN * 4);
    int* csr = (int*)alloc((size_t)GE * 4);  // 3.2 MB
    float* gs0 = (float*)alloc(128 * 4);
    float* gq0 = (float*)alloc(128 * 4);
    float* gs1 = (float*)alloc(128 * 4);
    float* gq1 = (float*)alloc(128 * 4);
    int* flag = (int*)alloc(4);
    hipMemsetAsync(zbase, 0, (size_t)(p - zbase), stream);

    detect_kernel<<<1, 256, 0, stream>>>((const unsigned short*)feat, flag);

    // CSR build + w-mean precompute (independent, early)
    const int NB = (GN + 255) / 256;  // 196 scan blocks
    count_kernel<<<(GE + 255) / 256, 256, 0, stream>>>(dst, deg, GE);
    scan1_kernel<<<NB, 256, 0, stream>>>(deg, cursor, bsum, GN);   // cursor = per-block incl scan
    scan2_kernel<<<1, 256, 0, stream>>>(bsum, NB);                 // bsum = exclusive block offs
    scan3_kernel<<<NB, 256, 0, stream>>>(deg, cursor, bsum, indptr, cursor, GN);
    scatter_kernel<<<(GE + 255) / 256, 256, 0, stream>>>(src, dst, cursor, csr, GE);
    wmean_kernel<<<24, 256, 0, stream>>>(w_lin2, wmt, flag);

    dim3 g2(782, 2), g3(782, 3);

    // ----- Layer 0 -----
    gemm_tile<<<g2, 256, 0, stream>>>(feat, 1, w_fc0, ftb, GN, 128, flag);
    gemm_tile<<<g2, 256, 0, stream>>>(feat, 1, w_lin0, hbuf, GN, 128, flag);  // skip0 -> hbuf
    elr_kernel<<<(GN * 4 + 255) / 256, 256, 0, stream>>>(ftb, al0, ar0, elb, erb, GN, 32, flag);
    agg_kernel<128, false><<<GN, 128, 0, stream>>>(ftb, elb, erb, indptr, csr, b0, nullptr,
                                                   hbuf, hbuf, nullptr, nullptr, flag);
    bn_stats<<<256, 128, 0, stream>>>(hbuf, gs0, gq0, GN);
    bn_apply<<<(GN * 128 + 255) / 256, 256, 0, stream>>>(hbuf, gs0, gq0, g0, be0, GN, flag);

    // ----- Layer 1 (h updated in place) -----
    gemm_tile<<<g2, 256, 0, stream>>>(hbuf, 0, w_fc1, ftb, GN, 128, flag);
    elr_kernel<<<(GN * 4 + 255) / 256, 256, 0, stream>>>(ftb, al1, ar1, elb, erb, GN, 32, flag);
    gemm_inplace<<<782, 256, 0, stream>>>(hbuf, w_lin1, GN, flag);  // hbuf <- h1 @ w_lin1
    agg_kernel<128, false><<<GN, 128, 0, stream>>>(ftb, elb, erb, indptr, csr, b1, nullptr,
                                                   hbuf, hbuf, nullptr, nullptr, flag);
    bn_stats<<<256, 128, 0, stream>>>(hbuf, gs1, gq1, GN);
    bn_apply<<<(GN * 128 + 255) / 256, 256, 0, stream>>>(hbuf, gs1, gq1, g1, be1, GN, flag);

    // ----- Layer 2 (final) -----
    gemm_tile<<<g3, 256, 0, stream>>>(hbuf, 0, w_fc2, ftb, GN, 160, flag);
    elr_kernel<<<(GN * 4 + 255) / 256, 256, 0, stream>>>(ftb, al2, ar2, elb, erb, GN, 40, flag);
    skipmean_inplace<<<782, 256, 0, stream>>>(hbuf, wmt, GN);  // hbuf[:,0:40] <- h2 @ wmean
    agg_kernel<160, true><<<GN, 192, 0, stream>>>(ftb, elb, erb, indptr, csr, b2, hbuf,
                                                  nullptr, nullptr, bias_last, d_out, flag);
}

// Round 2
// 763.433 us; speedup vs baseline: 1.1857x; 1.0778x over previous
//
#include <hip/hip_runtime.h>
#include <hip/hip_bf16.h>

#define GN 50000
#define GE 800000
#define GH 4
#define GFH 32
#define GC 40
#define GIN 128

typedef __hip_bfloat16 bf16;
typedef __attribute__((ext_vector_type(8))) short bf16x8;
typedef __attribute__((ext_vector_type(4))) float f32x4;

// mode m: 0 = tensor stored as bf16, 1 = stored as fp32
static __device__ __forceinline__ float ldx(const void* p, size_t i, int m) {
    if (m) return ((const float*)p)[i];
    return __bfloat162float(((const bf16*)p)[i]);
}
static __device__ __forceinline__ void stx(void* p, size_t i, int m, float v) {
    if (m) ((float*)p)[i] = v;
    else ((bf16*)p)[i] = __float2bfloat16(v);
}
static __device__ __forceinline__ unsigned short f2bfu(float v) {
    union { bf16 b; unsigned short u; } cv;
    cv.b = __float2bfloat16(v);
    return cv.u;
}
static __device__ __forceinline__ float lo16(unsigned u) { return __uint_as_float(u << 16); }
static __device__ __forceinline__ float hi16(unsigned u) { return __uint_as_float(u & 0xFFFF0000u); }
static __device__ __forceinline__ float guard_finite(float v) {
    if (!(v == v) || fabsf(v) > 1e30f) return 0.f;
    return v;
}

// ---------------- dtype probe: fp32 misread as bf16 shows wild exponents ----------------
__global__ void detect_kernel(const unsigned short* __restrict__ f, int* __restrict__ flag) {
    int t = threadIdx.x;  // 256
    unsigned short u = f[t];
    int e = (u >> 7) & 0xFF;
    if (e >= 0x8E) atomicAdd(flag, 1);  // |val| >= 2^15 or inf/nan -> not sane bf16 data
}

__global__ void sentinel_kernel(unsigned short* __restrict__ o, int n) {
    int i = blockIdx.x * blockDim.x + threadIdx.x;
    if (i < n) o[i] = 0x3F80;  // bf16 1.0
}

// ---------------- CSR build ----------------
__global__ void count_kernel(const int* __restrict__ dst, int* __restrict__ deg, int n) {
    int e = blockIdx.x * blockDim.x + threadIdx.x;
    if (e < n) {
        int d = dst[e];
        if (d >= 0 && d < GN) atomicAdd(&deg[d], 1);
    }
}

// ---- 3-pass device-wide scan ----
__global__ void scan1_kernel(const int* __restrict__ deg, int* __restrict__ tmp,
                             int* __restrict__ bsum, int n) {
    int tid = threadIdx.x;
    int i = blockIdx.x * 256 + tid;
    int v = (i < n) ? deg[i] : 0;
    int lane = tid & 63, wid = tid >> 6;
    int s = v;
#pragma unroll
    for (int off = 1; off < 64; off <<= 1) {
        int u = __shfl_up(s, off);
        if (lane >= off) s += u;
    }
    __shared__ int wsum[4];
    if (lane == 63) wsum[wid] = s;
    __syncthreads();
    int woff = 0;
#pragma unroll
    for (int w = 0; w < 4; w++) woff += (w < wid) ? wsum[w] : 0;
    int incl = s + woff;
    if (i < n) tmp[i] = incl;
    if (tid == 255) bsum[blockIdx.x] = incl;  // block total (zeros padded past n)
}

__global__ void scan2_kernel(int* __restrict__ bsum, int nb) {
    int tid = threadIdx.x;
    int v = (tid < nb) ? bsum[tid] : 0;
    int lane = tid & 63, wid = tid >> 6;
    int s = v;
#pragma unroll
    for (int off = 1; off < 64; off <<= 1) {
        int u = __shfl_up(s, off);
        if (lane >= off) s += u;
    }
    __shared__ int wsum[4];
    if (lane == 63) wsum[wid] = s;
    __syncthreads();
    int woff = 0;
#pragma unroll
    for (int w = 0; w < 4; w++) woff += (w < wid) ? wsum[w] : 0;
    if (tid < nb) bsum[tid] = s + woff - v;  // exclusive
}

__global__ void scan3_kernel(const int* __restrict__ deg, const int* __restrict__ tmp,
                             const int* __restrict__ bsum, int* __restrict__ indptr,
                             int* __restrict__ cursor, int n) {
    int i = blockIdx.x * 256 + threadIdx.x;
    if (i < n) {
        int incl = tmp[i] + bsum[blockIdx.x];
        indptr[i + 1] = incl;
        cursor[i] = incl - deg[i];
        if (i == 0) indptr[0] = 0;
    }
}

__global__ void scatter_kernel(const int* __restrict__ src, const int* __restrict__ dst,
                               int* __restrict__ cursor, int* __restrict__ csr_src, int n) {
    int e = blockIdx.x * blockDim.x + threadIdx.x;
    if (e < n) {
        int d = dst[e];
        if (d < 0 || d >= GN) return;
        int p = atomicAdd(&cursor[d], 1);
        if (p >= 0 && p < GE) csr_src[p] = src[e];
    }
}

// ---------------- w-mean: wmt[c][128] (c<48, zero-pad c>=40) = mean_h w_lin2[k][h*40+c] ----------------
__global__ void wmean_kernel(const void* __restrict__ w, unsigned short* __restrict__ wmt,
                             const int* __restrict__ flag) {
    int m = (*flag != 0) ? 1 : 0;
    int idx = blockIdx.x * blockDim.x + threadIdx.x;
    if (idx < 48 * 128) {
        int c = idx >> 7, k = idx & 127;
        float s = 0.f;
        if (c < 40) {
            s = 0.25f * (ldx(w, (size_t)k * 160 + c, m) + ldx(w, (size_t)k * 160 + 40 + c, m) +
                         ldx(w, (size_t)k * 160 + 80 + c, m) + ldx(w, (size_t)k * 160 + 120 + c, m));
        }
        wmt[c * 128 + k] = f2bfu(s);
    }
}

// ---------------- MFMA GEMM: Y[N,M](bf16) = X[N,128] @ W[128,M] ----------------
__global__ __launch_bounds__(256) void gemm_tile(const void* __restrict__ X, int xext,
                                                 const void* __restrict__ W,
                                                 bf16* __restrict__ Y, int nrows, int M,
                                                 const int* __restrict__ flag) {
    constexpr int LDX = 136;  // bf16 units; pad 8 -> 2-way LDS conflict only (free)
    __shared__ unsigned short Xs[64 * LDX];  // [r][k]
    __shared__ unsigned short Wt[64 * LDX];  // [c][k]
    int m = (*flag != 0) ? 1 : 0;
    int mx_ = xext ? m : 0;
    int tid = threadIdx.x;
    int rb = blockIdx.x * 64, cb = blockIdx.y * 64;

    for (int idx = tid; idx < 64 * 128; idx += 256) {
        int r = idx >> 7, k = idx & 127;
        int row = rb + r;
        Xs[r * LDX + k] =
            (row < nrows) ? f2bfu(ldx(X, (size_t)row * 128 + k, mx_)) : (unsigned short)0;
    }
    for (int idx = tid; idx < 128 * 64; idx += 256) {
        int k = idx >> 6, c = idx & 63;
        int col = cb + c;
        Wt[c * LDX + k] = (col < M) ? f2bfu(ldx(W, (size_t)k * M + col, m)) : (unsigned short)0;
    }
    __syncthreads();

    int wave = tid >> 6, lane = tid & 63;
    int lr = lane & 15, quad = lane >> 4;
    int mrow = wave * 16 + lr;

    f32x4 acc[4] = {};
    for (int kk = 0; kk < 128; kk += 32) {
        bf16x8 a = *(const bf16x8*)&Xs[mrow * LDX + kk + quad * 8];
#pragma unroll
        for (int nt = 0; nt < 4; nt++) {
            bf16x8 b = *(const bf16x8*)&Wt[(nt * 16 + lr) * LDX + kk + quad * 8];
            acc[nt] = __builtin_amdgcn_mfma_f32_16x16x32_bf16(a, b, acc[nt], 0, 0, 0);
        }
    }

    int drow = rb + wave * 16 + quad * 4;
#pragma unroll
    for (int nt = 0; nt < 4; nt++) {
        int col = cb + nt * 16 + lr;
#pragma unroll
        for (int i = 0; i < 4; i++) {
            int row = drow + i;
            if (row < nrows && col < M) Y[(size_t)row * M + col] = __float2bfloat16(acc[nt][i]);
        }
    }
}

// ---------------- MFMA in-place GEMM: X[nrows,128] <- X @ W[128,128] ----------------
__global__ __launch_bounds__(256) void gemm_inplace(bf16* __restrict__ X,
                                                    const void* __restrict__ W, int nrows,
                                                    const int* __restrict__ flag) {
    constexpr int LDX = 136;
    __shared__ unsigned short Xs[64 * LDX];    // [r][k]
    __shared__ unsigned short Wt[128 * LDX];   // [c][k]
    int m = (*flag != 0) ? 1 : 0;
    int tid = threadIdx.x;
    int rb = blockIdx.x * 64;

    for (int idx = tid; idx < 64 * 128; idx += 256) {
        int r = idx >> 7, k = idx & 127;
        int row = rb + r;
        Xs[r * LDX + k] =
            (row < nrows) ? ((const unsigned short*)X)[(size_t)row * 128 + k] : (unsigned short)0;
    }
    for (int idx = tid; idx < 128 * 128; idx += 256) {
        int k = idx >> 7, c = idx & 127;
        Wt[c * LDX + k] = f2bfu(ldx(W, (size_t)k * 128 + c, m));
    }
    __syncthreads();

    int wave = tid >> 6, lane = tid & 63;
    int lr = lane & 15, quad = lane >> 4;
    int mrow = wave * 16 + lr;

    f32x4 acc[8] = {};
    for (int kk = 0; kk < 128; kk += 32) {
        bf16x8 a = *(const bf16x8*)&Xs[mrow * LDX + kk + quad * 8];
#pragma unroll
        for (int nt = 0; nt < 8; nt++) {
            bf16x8 b = *(const bf16x8*)&Wt[(nt * 16 + lr) * LDX + kk + quad * 8];
            acc[nt] = __builtin_amdgcn_mfma_f32_16x16x32_bf16(a, b, acc[nt], 0, 0, 0);
        }
    }

    int drow = rb + wave * 16 + quad * 4;
#pragma unroll
    for (int nt = 0; nt < 8; nt++) {
        int col = nt * 16 + lr;
#pragma unroll
        for (int i = 0; i < 4; i++) {
            int row = drow + i;
            if (row < nrows) X[(size_t)row * 128 + col] = __float2bfloat16(acc[nt][i]);
        }
    }
}

// ---------------- skipmean in-place: X[:,0:40] <- X @ wmt^T (wmt: [48][128]) ----------------
__global__ __launch_bounds__(256) void skipmean_inplace(bf16* __restrict__ X,
                                                        const unsigned short* __restrict__ wmt,
                                                        int nrows) {
    constexpr int LDX = 136;
    __shared__ unsigned short Xs[64 * LDX];  // [r][k]
    __shared__ unsigned short Wt[48 * LDX];  // [c][k]
    int tid = threadIdx.x;
    int rb = blockIdx.x * 64;

    for (int idx = tid; idx < 64 * 128; idx += 256) {
        int r = idx >> 7, k = idx & 127;
        int row = rb + r;
        Xs[r * LDX + k] =
            (row < nrows) ? ((const unsigned short*)X)[(size_t)row * 128 + k] : (unsigned short)0;
    }
    for (int idx = tid; idx < 48 * 128; idx += 256) {
        int c = idx >> 7, k = idx & 127;
        Wt[c * LDX + k] = wmt[c * 128 + k];
    }
    __syncthreads();

    int wave = tid >> 6, lane = tid & 63;
    int lr = lane & 15, quad = lane >> 4;
    int mrow = wave * 16 + lr;

    f32x4 acc[3] = {};
    for (int kk = 0; kk < 128; kk += 32) {
        bf16x8 a = *(const bf16x8*)&Xs[mrow * LDX + kk + quad * 8];
#pragma unroll
        for (int nt = 0; nt < 3; nt++) {
            bf16x8 b = *(const bf16x8*)&Wt[(nt * 16 + lr) * LDX + kk + quad * 8];
            acc[nt] = __builtin_amdgcn_mfma_f32_16x16x32_bf16(a, b, acc[nt], 0, 0, 0);
        }
    }

    int drow = rb + wave * 16 + quad * 4;
#pragma unroll
    for (int nt = 0; nt < 3; nt++) {
        int col = nt * 16 + lr;
        if (col < 40) {
#pragma unroll
            for (int i = 0; i < 4; i++) {
                int row = drow + i;
                if (row < nrows) X[(size_t)row * 128 + col] = __float2bfloat16(acc[nt][i]);
            }
        }
    }
}

// ---------------- el/er: [N,H] dot over F (vectorized bf16x8 loads) ----------------
__global__ void elr_kernel(const bf16* __restrict__ ft, const void* __restrict__ al,
                           const void* __restrict__ ar, float* __restrict__ el,
                           float* __restrict__ er, int n, int F, const int* __restrict__ flag) {
    int m = (*flag != 0) ? 1 : 0;
    int gid = blockIdx.x * blockDim.x + threadIdx.x;
    if (gid >= n * 4) return;
    int nid = gid >> 2, h = gid & 3;
    const bf16* f = ft + (size_t)nid * (4 * F) + h * F;
    float sl = 0.f, sr = 0.f;
    for (int i0 = 0; i0 < F; i0 += 8) {
        bf16x8 v8 = *(const bf16x8*)(f + i0);
#pragma unroll
        for (int i = 0; i < 8; i++) {
            float v = __uint_as_float(((unsigned)(unsigned short)v8[i]) << 16);
            sl += v * ldx(al, h * F + i0 + i, m);
            sr += v * ldx(ar, h * F + i0 + i, m);
        }
    }
    el[gid] = sl;
    er[gid] = sr;
}

// ---------------- per-dst softmax + aggregation: ONE WAVE PER NODE, zero barriers ----------------
// Weight phase: 16 edges x 4 heads = 64 lanes (lane = j*4 + h); w,u stay in registers.
// Gather phase: lane owns feature pair c0 = 2*lane (FINAL: lanes 0-15 also own pair 128+2*lane).
//   u broadcast via shfl+readfirstlane (scalar base -> one coalesced row load per edge);
//   w[edge][h0] via one shfl per edge. s-reduction: 4-step shfl_xor butterfly.
// out may alias skip_pre: same lane reads skip pair before writing out pair (program order).
template <int FTOT, bool FINAL>
__global__ __launch_bounds__(256) void agg_wave(
    const bf16* __restrict__ ft, const float* __restrict__ el, const float* __restrict__ er,
    const int* __restrict__ indptr, const int* __restrict__ csr_src,
    const void* __restrict__ bias, const void* __restrict__ h_in,
    const bf16* __restrict__ skip_pre, bf16* __restrict__ out,
    const void* __restrict__ bias_last, void* __restrict__ fout,
    const int* __restrict__ flag) {
    constexpr int HF = FTOT / 4;
    int m = (*flag != 0) ? 1 : 0;
    int lane = threadIdx.x & 63;
    int v = blockIdx.x * 4 + (threadIdx.x >> 6);
    if (v >= GN) return;
    int beg = indptr[v], end = indptr[v + 1];
    beg = max(0, min(beg, GE));
    end = max(beg, min(end, GE));

    int h = lane & 3, jl = lane >> 2;  // weight-phase mapping: edge slot jl, head h
    int c0 = 2 * lane;                 // gather-phase feature pair
    int h0 = c0 / HF;
    float erv = er[v * 4 + h];

    float a0 = 0.f, a1 = 0.f, a2 = 0.f, a3 = 0.f;
    float s_part = 0.f;

    for (int cb = beg; cb < end; cb += 16) {
        int chn = end - cb;
        chn = chn < 16 ? chn : 16;
        // ---- weight phase (this chunk's 16 edges) ----
        int u = csr_src[cb + (jl < chn ? jl : chn - 1)];
        u = min(max(u, 0), GN - 1);
        float e = el[u * 4 + h] + erv;
        e = e > 0.f ? e : 0.2f * e;
        float w = (jl < chn) ? __expf(fminf(e, 60.f)) : 0.f;
        s_part += w;
        // ---- gather phase: groups of 4 edges, uniform early-out; w=0 pads OOB ----
        for (int j4 = 0; j4 < 16; j4 += 4) {
            if (j4 >= chn) break;  // wave-uniform
#pragma unroll
            for (int q = 0; q < 4; q++) {
                int sl_ = (j4 + q) * 4;
                int us = __builtin_amdgcn_readfirstlane(__shfl(u, sl_));
                float wq = __shfl(w, sl_ + h0);
                unsigned p = *(const unsigned*)(ft + (size_t)us * FTOT + c0);
                a0 += wq * lo16(p);
                a1 += wq * hi16(p);
                if constexpr (FINAL) {
                    float wb = __shfl(w, sl_ + 3);  // pair1 cols 128..159 are head 3
                    if (lane < 16) {
                        unsigned pb = *(const unsigned*)(ft + (size_t)us * FTOT + 128 + c0);
                        a2 += wb * lo16(pb);
                        a3 += wb * hi16(pb);
                    }
                }
            }
        }
    }

    // ---- s reduction: butterfly over slot bits (head preserved in lane&3) ----
#pragma unroll
    for (int off = 4; off < 64; off <<= 1) s_part += __shfl_xor(s_part, off);
    float s0 = __shfl(s_part, h0);  // lane h0 (0..3) holds head-h0 total

    float r0 = (s0 > 0.f) ? a0 / s0 : 0.f;
    float r1 = (s0 > 0.f) ? a1 / s0 : 0.f;

    if constexpr (!FINAL) {
        unsigned pk = *(const unsigned*)(skip_pre + (size_t)v * FTOT + c0);
        float o0 = r0 + ldx(bias, c0, m) + lo16(pk);
        float o1 = r1 + ldx(bias, c0 + 1, m) + hi16(pk);
        unsigned po = ((unsigned)f2bfu(guard_finite(o1)) << 16) |
                      (unsigned)f2bfu(guard_finite(o0));
        *(unsigned*)(out + (size_t)v * FTOT + c0) = po;
    } else {
        float s3 = __shfl(s_part, 3);
        float o0 = r0 + ldx(bias, c0, m);
        float o1 = r1 + ldx(bias, c0 + 1, m);
        float r2 = (s3 > 0.f) ? a2 / s3 : 0.f;
        float r3 = (s3 > 0.f) ? a3 / s3 : 0.f;
        int cb0 = 128 + c0;  // meaningful for lane<16 only
        float o2 = r2 + ldx(bias, (cb0 < FTOT) ? cb0 : 0, m);
        float o3 = r3 + ldx(bias, (cb0 + 1 < FTOT) ? cb0 + 1 : 1, m);

        // head-average: lane t<40 needs cols t, t+40, t+80, t+120 (all parity t&1)
        int t = lane;
        bool od = (t & 1);
        int sA = (t >> 1) & 63;
        int sB = ((t + 40) >> 1) & 63;
        int sC = ((t + 80) >> 1) & 63;
        int sD1 = ((t + 120) >> 1) & 63;          // valid when t<8 (col<128, from o0/o1)
        int sD2 = ((t >= 8 ? t - 8 : 0) >> 1);    // valid when t>=8 (col>=128, from o2/o3)
        float vA0 = __shfl(o0, sA), vA1 = __shfl(o1, sA);
        float vB0 = __shfl(o0, sB), vB1 = __shfl(o1, sB);
        float vC0 = __shfl(o0, sC), vC1 = __shfl(o1, sC);
        float vD10 = __shfl(o0, sD1), vD11 = __shfl(o1, sD1);
        float vD20 = __shfl(o2, sD2), vD21 = __shfl(o3, sD2);
        float vA = od ? vA1 : vA0;
        float vB = od ? vB1 : vB0;
        float vC = od ? vC1 : vC0;
        float vD = (t < 8) ? (od ? vD11 : vD10) : (od ? vD21 : vD20);

        float x = -3.0e38f;
        if (t < 40) {
            float sm = __bfloat162float(((const bf16*)h_in)[(size_t)v * 128 + t]);
            x = 0.25f * (vA + vB + vC + vD) + sm + ldx(bias_last, t, m);
        }
        float mx = x;
#pragma unroll
        for (int off = 1; off < 64; off <<= 1) mx = fmaxf(mx, __shfl_xor(mx, off));
        float ex = (t < 40) ? __expf(x - mx) : 0.f;
        float sum = ex;
#pragma unroll
        for (int off = 1; off < 64; off <<= 1) sum += __shfl_xor(sum, off);
        if (t < 40) stx(fout, (size_t)v * 40 + t, m, guard_finite(x - mx - __logf(sum)));
    }
}

// ---------------- BatchNorm (+ ReLU) on bf16 [N,128] ----------------
__global__ void bn_stats(const bf16* __restrict__ x, float* __restrict__ gsum,
                         float* __restrict__ gsq, int n) {
    int c = threadIdx.x;  // 128
    int rows_per_block = (n + gridDim.x - 1) / gridDim.x;
    int r0 = blockIdx.x * rows_per_block;
    int r1 = min(n, r0 + rows_per_block);
    float s = 0.f, q = 0.f;
    for (int r = r0; r < r1; r++) {
        float v = __bfloat162float(x[(size_t)r * 128 + c]);
        s += v;
        q += v * v;
    }
    atomicAdd(&gsum[c], s);
    atomicAdd(&gsq[c], q);
}

__global__ void bn_apply(bf16* __restrict__ x, const float* __restrict__ gsum,
                         const float* __restrict__ gsq, const void* __restrict__ g,
                         const void* __restrict__ be, int n, const int* __restrict__ flag) {
    int m = (*flag != 0) ? 1 : 0;
    int gid = blockIdx.x * blockDim.x + threadIdx.x;
    if (gid >= n * 128) return;
    int c = gid & 127;
    float inv_n = 1.f / (float)n;
    float mu = gsum[c] * inv_n;
    float var = gsq[c] * inv_n - mu * mu;
    float y = (__bfloat162float(x[gid]) - mu) * rsqrtf(fmaxf(var, 0.f) + 1e-5f) * ldx(g, c, m) +
              ldx(be, c, m);
    x[gid] = __float2bfloat16(y > 0.f ? y : 0.f);
}

extern "C" void kernel_launch(void* const* d_in, const int* in_sizes, int n_in,
                              void* d_out, int out_size, void* d_ws, size_t ws_size,
                              hipStream_t stream) {
    const void* feat = d_in[0];
    const int* src = (const int*)d_in[1];
    const int* dst = (const int*)d_in[2];
    const void* w_fc0 = d_in[3];
    const void* al0 = d_in[4];
    const void* ar0 = d_in[5];
    const void* b0 = d_in[6];
    const void* w_lin0 = d_in[7];
    const void* g0 = d_in[8];
    const void* be0 = d_in[9];
    const void* w_fc1 = d_in[10];
    const void* al1 = d_in[11];
    const void* ar1 = d_in[12];
    const void* b1 = d_in[13];
    const void* w_lin1 = d_in[14];
    const void* g1 = d_in[15];
    const void* be1 = d_in[16];
    const void* w_fc2 = d_in[17];
    const void* al2 = d_in[18];
    const void* ar2 = d_in[19];
    const void* b2 = d_in[20];
    const void* w_lin2 = d_in[21];
    const void* bias_last = d_in[22];

    // ---- workspace guard: total need ~34.5 MB ----
    if (ws_size < 35000000) {
        sentinel_kernel<<<(out_size + 255) / 256, 256, 0, stream>>>((unsigned short*)d_out,
                                                                    out_size);
        return;
    }

    char* p = (char*)d_ws;
    auto alloc = [&](size_t bytes) {
        char* r = p;
        p += (bytes + 255) & ~(size_t)255;
        return r;
    };
    bf16* ftb = (bf16*)alloc((size_t)GN * 160 * 2);   // 16.0 MB
    bf16* hbuf = (bf16*)alloc((size_t)GN * 128 * 2);  // 12.8 MB
    float* elb = (float*)alloc((size_t)GN * 4 * 4);   // 0.8 MB
    float* erb = (float*)alloc((size_t)GN * 4 * 4);   // 0.8 MB
    int* indptr = (int*)alloc((size_t)(GN + 1) * 4);
    int* cursor = (int*)alloc((size_t)GN * 4);
    int* bsum = (int*)alloc(256 * 4);                 // block sums for 3-pass scan
    unsigned short* wmt = (unsigned short*)alloc(48 * 128 * 2);  // 12.3 KB
    char* zbase = p;  // ---- zero-initialized region ----
    int* deg = (int*)alloc((size_t)GN * 4);
    int* csr = (int*)alloc((size_t)GE * 4);  // 3.2 MB
    float* gs0 = (float*)alloc(128 * 4);
    float* gq0 = (float*)alloc(128 * 4);
    float* gs1 = (float*)alloc(128 * 4);
    float* gq1 = (float*)alloc(128 * 4);
    int* flag = (int*)alloc(4);
    hipMemsetAsync(zbase, 0, (size_t)(p - zbase), stream);

    detect_kernel<<<1, 256, 0, stream>>>((const unsigned short*)feat, flag);

    // CSR build + w-mean precompute (independent, early)
    const int NB = (GN + 255) / 256;  // 196 scan blocks
    count_kernel<<<(GE + 255) / 256, 256, 0, stream>>>(dst, deg, GE);
    scan1_kernel<<<NB, 256, 0, stream>>>(deg, cursor, bsum, GN);   // cursor = per-block incl scan
    scan2_kernel<<<1, 256, 0, stream>>>(bsum, NB);                 // bsum = exclusive block offs
    scan3_kernel<<<NB, 256, 0, stream>>>(deg, cursor, bsum, indptr, cursor, GN);
    scatter_kernel<<<(GE + 255) / 256, 256, 0, stream>>>(src, dst, cursor, csr, GE);
    wmean_kernel<<<24, 256, 0, stream>>>(w_lin2, wmt, flag);

    dim3 g2(782, 2), g3(782, 3);
    const int AGGB = (GN + 3) / 4;  // 12500 blocks, 4 waves (nodes) each

    // ----- Layer 0 -----
    gemm_tile<<<g2, 256, 0, stream>>>(feat, 1, w_fc0, ftb, GN, 128, flag);
    gemm_tile<<<g2, 256, 0, stream>>>(feat, 1, w_lin0, hbuf, GN, 128, flag);  // skip0 -> hbuf
    elr_kernel<<<(GN * 4 + 255) / 256, 256, 0, stream>>>(ftb, al0, ar0, elb, erb, GN, 32, flag);
    agg_wave<128, false><<<AGGB, 256, 0, stream>>>(ftb, elb, erb, indptr, csr, b0, nullptr,
                                                   hbuf, hbuf, nullptr, nullptr, flag);
    bn_stats<<<256, 128, 0, stream>>>(hbuf, gs0, gq0, GN);
    bn_apply<<<(GN * 128 + 255) / 256, 256, 0, stream>>>(hbuf, gs0, gq0, g0, be0, GN, flag);

    // ----- Layer 1 (h updated in place) -----
    gemm_tile<<<g2, 256, 0, stream>>>(hbuf, 0, w_fc1, ftb, GN, 128, flag);
    elr_kernel<<<(GN * 4 + 255) / 256, 256, 0, stream>>>(ftb, al1, ar1, elb, erb, GN, 32, flag);
    gemm_inplace<<<782, 256, 0, stream>>>(hbuf, w_lin1, GN, flag);  // hbuf <- h1 @ w_lin1
    agg_wave<128, false><<<AGGB, 256, 0, stream>>>(ftb, elb, erb, indptr, csr, b1, nullptr,
                                                   hbuf, hbuf, nullptr, nullptr, flag);
    bn_stats<<<256, 128, 0, stream>>>(hbuf, gs1, gq1, GN);
    bn_apply<<<(GN * 128 + 255) / 256, 256, 0, stream>>>(hbuf, gs1, gq1, g1, be1, GN, flag);

    // ----- Layer 2 (final) -----
    gemm_tile<<<g3, 256, 0, stream>>>(hbuf, 0, w_fc2, ftb, GN, 160, flag);
    elr_kernel<<<(GN * 4 + 255) / 256, 256, 0, stream>>>(ftb, al2, ar2, elb, erb, GN, 40, flag);
    skipmean_inplace<<<782, 256, 0, stream>>>(hbuf, wmt, GN);  // hbuf[:,0:40] <- h2 @ wmean
    agg_wave<160, true><<<AGGB, 256, 0, stream>>>(ftb, elb, erb, indptr, csr, b2, hbuf,
                                                  nullptr, nullptr, bias_last, d_out, flag);
}

// Round 3
// 724.752 us; speedup vs baseline: 1.2490x; 1.0534x over previous
//
#include <hip/hip_runtime.h>
#include <hip/hip_bf16.h>

#define GN 50000
#define GE 800000
#define GH 4
#define GFH 32
#define GC 40
#define GIN 128

typedef __hip_bfloat16 bf16;
typedef __attribute__((ext_vector_type(8))) short bf16x8;
typedef __attribute__((ext_vector_type(4))) float f32x4;

// mode m: 0 = tensor stored as bf16, 1 = stored as fp32
static __device__ __forceinline__ float ldx(const void* p, size_t i, int m) {
    if (m) return ((const float*)p)[i];
    return __bfloat162float(((const bf16*)p)[i]);
}
static __device__ __forceinline__ void stx(void* p, size_t i, int m, float v) {
    if (m) ((float*)p)[i] = v;
    else ((bf16*)p)[i] = __float2bfloat16(v);
}
static __device__ __forceinline__ unsigned short f2bfu(float v) {
    union { bf16 b; unsigned short u; } cv;
    cv.b = __float2bfloat16(v);
    return cv.u;
}
static __device__ __forceinline__ float lo16(unsigned u) { return __uint_as_float(u << 16); }
static __device__ __forceinline__ float hi16(unsigned u) { return __uint_as_float(u & 0xFFFF0000u); }
static __device__ __forceinline__ float guard_finite(float v) {
    if (!(v == v) || fabsf(v) > 1e30f) return 0.f;
    return v;
}

// ---------------- dtype probe: fp32 misread as bf16 shows wild exponents ----------------
__global__ void detect_kernel(const unsigned short* __restrict__ f, int* __restrict__ flag) {
    int t = threadIdx.x;  // 256
    unsigned short u = f[t];
    int e = (u >> 7) & 0xFF;
    if (e >= 0x8E) atomicAdd(flag, 1);  // |val| >= 2^15 or inf/nan -> not sane bf16 data
}

__global__ void sentinel_kernel(unsigned short* __restrict__ o, int n) {
    int i = blockIdx.x * blockDim.x + threadIdx.x;
    if (i < n) o[i] = 0x3F80;  // bf16 1.0
}

// ---------------- CSR build ----------------
__global__ void count_kernel(const int* __restrict__ dst, int* __restrict__ deg, int n) {
    int e = blockIdx.x * blockDim.x + threadIdx.x;
    if (e < n) {
        int d = dst[e];
        if (d >= 0 && d < GN) atomicAdd(&deg[d], 1);
    }
}

// ---- 3-pass device-wide scan ----
__global__ void scan1_kernel(const int* __restrict__ deg, int* __restrict__ tmp,
                             int* __restrict__ bsum, int n) {
    int tid = threadIdx.x;
    int i = blockIdx.x * 256 + tid;
    int v = (i < n) ? deg[i] : 0;
    int lane = tid & 63, wid = tid >> 6;
    int s = v;
#pragma unroll
    for (int off = 1; off < 64; off <<= 1) {
        int u = __shfl_up(s, off);
        if (lane >= off) s += u;
    }
    __shared__ int wsum[4];
    if (lane == 63) wsum[wid] = s;
    __syncthreads();
    int woff = 0;
#pragma unroll
    for (int w = 0; w < 4; w++) woff += (w < wid) ? wsum[w] : 0;
    int incl = s + woff;
    if (i < n) tmp[i] = incl;
    if (tid == 255) bsum[blockIdx.x] = incl;  // block total (zeros padded past n)
}

__global__ void scan2_kernel(int* __restrict__ bsum, int nb) {
    int tid = threadIdx.x;
    int v = (tid < nb) ? bsum[tid] : 0;
    int lane = tid & 63, wid = tid >> 6;
    int s = v;
#pragma unroll
    for (int off = 1; off < 64; off <<= 1) {
        int u = __shfl_up(s, off);
        if (lane >= off) s += u;
    }
    __shared__ int wsum[4];
    if (lane == 63) wsum[wid] = s;
    __syncthreads();
    int woff = 0;
#pragma unroll
    for (int w = 0; w < 4; w++) woff += (w < wid) ? wsum[w] : 0;
    if (tid < nb) bsum[tid] = s + woff - v;  // exclusive
}

__global__ void scan3_kernel(const int* __restrict__ deg, const int* __restrict__ tmp,
                             const int* __restrict__ bsum, int* __restrict__ indptr,
                             int* __restrict__ cursor, int n) {
    int i = blockIdx.x * 256 + threadIdx.x;
    if (i < n) {
        int incl = tmp[i] + bsum[blockIdx.x];
        indptr[i + 1] = incl;
        cursor[i] = incl - deg[i];
        if (i == 0) indptr[0] = 0;
    }
}

__global__ void scatter_kernel(const int* __restrict__ src, const int* __restrict__ dst,
                               int* __restrict__ cursor, int* __restrict__ csr_src, int n) {
    int e = blockIdx.x * blockDim.x + threadIdx.x;
    if (e < n) {
        int d = dst[e];
        if (d < 0 || d >= GN) return;
        int p = atomicAdd(&cursor[d], 1);
        if (p >= 0 && p < GE) csr_src[p] = src[e];
    }
}

// ---------------- w-mean: wmt[c][128] (c<48, zero-pad c>=40) = mean_h w_lin2[k][h*40+c] ----------------
__global__ void wmean_kernel(const void* __restrict__ w, unsigned short* __restrict__ wmt,
                             const int* __restrict__ flag) {
    int m = (*flag != 0) ? 1 : 0;
    int idx = blockIdx.x * blockDim.x + threadIdx.x;
    if (idx < 48 * 128) {
        int c = idx >> 7, k = idx & 127;
        float s = 0.f;
        if (c < 40) {
            s = 0.25f * (ldx(w, (size_t)k * 160 + c, m) + ldx(w, (size_t)k * 160 + 40 + c, m) +
                         ldx(w, (size_t)k * 160 + 80 + c, m) + ldx(w, (size_t)k * 160 + 120 + c, m));
        }
        wmt[c * 128 + k] = f2bfu(s);
    }
}

// ---------------- MFMA GEMM: Y[N,M](bf16) = X[N,128] @ W[128,M] ----------------
__global__ __launch_bounds__(256) void gemm_tile(const void* __restrict__ X, int xext,
                                                 const void* __restrict__ W,
                                                 bf16* __restrict__ Y, int nrows, int M,
                                                 const int* __restrict__ flag) {
    constexpr int LDX = 136;  // bf16 units; pad 8 -> 2-way LDS conflict only (free)
    __shared__ unsigned short Xs[64 * LDX];  // [r][k]
    __shared__ unsigned short Wt[64 * LDX];  // [c][k]
    int m = (*flag != 0) ? 1 : 0;
    int mx_ = xext ? m : 0;
    int tid = threadIdx.x;
    int rb = blockIdx.x * 64, cb = blockIdx.y * 64;

    for (int idx = tid; idx < 64 * 128; idx += 256) {
        int r = idx >> 7, k = idx & 127;
        int row = rb + r;
        Xs[r * LDX + k] =
            (row < nrows) ? f2bfu(ldx(X, (size_t)row * 128 + k, mx_)) : (unsigned short)0;
    }
    for (int idx = tid; idx < 128 * 64; idx += 256) {
        int k = idx >> 6, c = idx & 63;
        int col = cb + c;
        Wt[c * LDX + k] = (col < M) ? f2bfu(ldx(W, (size_t)k * M + col, m)) : (unsigned short)0;
    }
    __syncthreads();

    int wave = tid >> 6, lane = tid & 63;
    int lr = lane & 15, quad = lane >> 4;
    int mrow = wave * 16 + lr;

    f32x4 acc[4] = {};
    for (int kk = 0; kk < 128; kk += 32) {
        bf16x8 a = *(const bf16x8*)&Xs[mrow * LDX + kk + quad * 8];
#pragma unroll
        for (int nt = 0; nt < 4; nt++) {
            bf16x8 b = *(const bf16x8*)&Wt[(nt * 16 + lr) * LDX + kk + quad * 8];
            acc[nt] = __builtin_amdgcn_mfma_f32_16x16x32_bf16(a, b, acc[nt], 0, 0, 0);
        }
    }

    int drow = rb + wave * 16 + quad * 4;
#pragma unroll
    for (int nt = 0; nt < 4; nt++) {
        int col = cb + nt * 16 + lr;
#pragma unroll
        for (int i = 0; i < 4; i++) {
            int row = drow + i;
            if (row < nrows && col < M) Y[(size_t)row * M + col] = __float2bfloat16(acc[nt][i]);
        }
    }
}

// ---------------- MFMA dual GEMM: Y1 = X@W1, Y2 = X@W2 (both 128x128); X staged once ----------------
// Y2 may alias X (in-place): each block reads/writes only its own 64 rows.
__global__ __launch_bounds__(256) void gemm_dual(const void* __restrict__ X, int xext,
                                                 const void* __restrict__ W1,
                                                 const void* __restrict__ W2,
                                                 bf16* __restrict__ Y1, bf16* __restrict__ Y2,
                                                 int nrows, const int* __restrict__ flag) {
    constexpr int LDX = 136;
    __shared__ unsigned short Xs[64 * LDX];   // [r][k]
    __shared__ unsigned short Wt[128 * LDX];  // [c][k], reused for W1 then W2
    int m = (*flag != 0) ? 1 : 0;
    int mx_ = xext ? m : 0;
    int tid = threadIdx.x;
    int rb = blockIdx.x * 64;

    for (int idx = tid; idx < 64 * 128; idx += 256) {
        int r = idx >> 7, k = idx & 127;
        int row = rb + r;
        Xs[r * LDX + k] =
            (row < nrows) ? f2bfu(ldx(X, (size_t)row * 128 + k, mx_)) : (unsigned short)0;
    }
    for (int idx = tid; idx < 128 * 128; idx += 256) {
        int k = idx >> 7, c = idx & 127;
        Wt[c * LDX + k] = f2bfu(ldx(W1, (size_t)k * 128 + c, m));
    }
    __syncthreads();

    int wave = tid >> 6, lane = tid & 63;
    int lr = lane & 15, quad = lane >> 4;
    int mrow = wave * 16 + lr;
    int drow = rb + wave * 16 + quad * 4;

    {
        f32x4 acc[8] = {};
        for (int kk = 0; kk < 128; kk += 32) {
            bf16x8 a = *(const bf16x8*)&Xs[mrow * LDX + kk + quad * 8];
#pragma unroll
            for (int nt = 0; nt < 8; nt++) {
                bf16x8 b = *(const bf16x8*)&Wt[(nt * 16 + lr) * LDX + kk + quad * 8];
                acc[nt] = __builtin_amdgcn_mfma_f32_16x16x32_bf16(a, b, acc[nt], 0, 0, 0);
            }
        }
#pragma unroll
        for (int nt = 0; nt < 8; nt++) {
            int col = nt * 16 + lr;
#pragma unroll
            for (int i = 0; i < 4; i++) {
                int row = drow + i;
                if (row < nrows) Y1[(size_t)row * 128 + col] = __float2bfloat16(acc[nt][i]);
            }
        }
    }
    __syncthreads();  // all waves done reading W1 tile
    for (int idx = tid; idx < 128 * 128; idx += 256) {
        int k = idx >> 7, c = idx & 127;
        Wt[c * LDX + k] = f2bfu(ldx(W2, (size_t)k * 128 + c, m));
    }
    __syncthreads();
    {
        f32x4 acc[8] = {};
        for (int kk = 0; kk < 128; kk += 32) {
            bf16x8 a = *(const bf16x8*)&Xs[mrow * LDX + kk + quad * 8];
#pragma unroll
            for (int nt = 0; nt < 8; nt++) {
                bf16x8 b = *(const bf16x8*)&Wt[(nt * 16 + lr) * LDX + kk + quad * 8];
                acc[nt] = __builtin_amdgcn_mfma_f32_16x16x32_bf16(a, b, acc[nt], 0, 0, 0);
            }
        }
#pragma unroll
        for (int nt = 0; nt < 8; nt++) {
            int col = nt * 16 + lr;
#pragma unroll
            for (int i = 0; i < 4; i++) {
                int row = drow + i;
                if (row < nrows) Y2[(size_t)row * 128 + col] = __float2bfloat16(acc[nt][i]);
            }
        }
    }
}

// ---------------- skipmean in-place: X[:,0:40] <- X @ wmt^T (wmt: [48][128]) ----------------
__global__ __launch_bounds__(256) void skipmean_inplace(bf16* __restrict__ X,
                                                        const unsigned short* __restrict__ wmt,
                                                        int nrows) {
    constexpr int LDX = 136;
    __shared__ unsigned short Xs[64 * LDX];  // [r][k]
    __shared__ unsigned short Wt[48 * LDX];  // [c][k]
    int tid = threadIdx.x;
    int rb = blockIdx.x * 64;

    for (int idx = tid; idx < 64 * 128; idx += 256) {
        int r = idx >> 7, k = idx & 127;
        int row = rb + r;
        Xs[r * LDX + k] =
            (row < nrows) ? ((const unsigned short*)X)[(size_t)row * 128 + k] : (unsigned short)0;
    }
    for (int idx = tid; idx < 48 * 128; idx += 256) {
        int c = idx >> 7, k = idx & 127;
        Wt[c * LDX + k] = wmt[c * 128 + k];
    }
    __syncthreads();

    int wave = tid >> 6, lane = tid & 63;
    int lr = lane & 15, quad = lane >> 4;
    int mrow = wave * 16 + lr;

    f32x4 acc[3] = {};
    for (int kk = 0; kk < 128; kk += 32) {
        bf16x8 a = *(const bf16x8*)&Xs[mrow * LDX + kk + quad * 8];
#pragma unroll
        for (int nt = 0; nt < 3; nt++) {
            bf16x8 b = *(const bf16x8*)&Wt[(nt * 16 + lr) * LDX + kk + quad * 8];
            acc[nt] = __builtin_amdgcn_mfma_f32_16x16x32_bf16(a, b, acc[nt], 0, 0, 0);
        }
    }

    int drow = rb + wave * 16 + quad * 4;
#pragma unroll
    for (int nt = 0; nt < 3; nt++) {
        int col = nt * 16 + lr;
        if (col < 40) {
#pragma unroll
            for (int i = 0; i < 4; i++) {
                int row = drow + i;
                if (row < nrows) X[(size_t)row * 128 + col] = __float2bfloat16(acc[nt][i]);
            }
        }
    }
}

// ---------------- el/er: [N,H] dot over F (vectorized bf16x8 loads) ----------------
__global__ void elr_kernel(const bf16* __restrict__ ft, const void* __restrict__ al,
                           const void* __restrict__ ar, float* __restrict__ el,
                           float* __restrict__ er, int n, int F, const int* __restrict__ flag) {
    int m = (*flag != 0) ? 1 : 0;
    int gid = blockIdx.x * blockDim.x + threadIdx.x;
    if (gid >= n * 4) return;
    int nid = gid >> 2, h = gid & 3;
    const bf16* f = ft + (size_t)nid * (4 * F) + h * F;
    float sl = 0.f, sr = 0.f;
    for (int i0 = 0; i0 < F; i0 += 8) {
        bf16x8 v8 = *(const bf16x8*)(f + i0);
#pragma unroll
        for (int i = 0; i < 8; i++) {
            float v = __uint_as_float(((unsigned)(unsigned short)v8[i]) << 16);
            sl += v * ldx(al, h * F + i0 + i, m);
            sr += v * ldx(ar, h * F + i0 + i, m);
        }
    }
    el[gid] = sl;
    er[gid] = sr;
}

// ---------------- per-dst softmax + aggregation: ONE WAVE PER NODE, zero barriers ----------------
// Weight phase: 16 edges x 4 heads = 64 lanes (lane = j*4 + h); w,u stay in registers.
// Gather phase (batched MLP): u broadcast via readlane (VALU->SGPR, no LDS pipe; address
//   independent of shuffle latency); 8 row-loads + 8 wq-shuffles issued per batch, then consumed.
// s-reduction: 4-step shfl_xor butterfly. out may alias skip_pre (same-lane read-then-write).
template <int FTOT, bool FINAL>
__global__ __launch_bounds__(256) void agg_wave(
    const bf16* __restrict__ ft, const float* __restrict__ el, const float* __restrict__ er,
    const int* __restrict__ indptr, const int* __restrict__ csr_src,
    const void* __restrict__ bias, const void* __restrict__ h_in,
    const bf16* __restrict__ skip_pre, bf16* __restrict__ out,
    const void* __restrict__ bias_last, void* __restrict__ fout,
    const int* __restrict__ flag) {
    constexpr int HF = FTOT / 4;
    int m = (*flag != 0) ? 1 : 0;
    int lane = threadIdx.x & 63;
    int v = blockIdx.x * 4 + (threadIdx.x >> 6);
    if (v >= GN) return;
    int beg = indptr[v], end = indptr[v + 1];
    beg = max(0, min(beg, GE));
    end = max(beg, min(end, GE));

    int h = lane & 3, jl = lane >> 2;  // weight-phase mapping: edge slot jl, head h
    int c0 = 2 * lane;                 // gather-phase feature pair
    int h0 = c0 / HF;
    float erv = er[v * 4 + h];

    float a0 = 0.f, a1 = 0.f, a2 = 0.f, a3 = 0.f;
    float s_part = 0.f;

    for (int cb = beg; cb < end; cb += 16) {
        int chn = end - cb;
        chn = chn < 16 ? chn : 16;
        // ---- weight phase (this chunk's 16 edges) ----
        int u = csr_src[cb + (jl < chn ? jl : chn - 1)];
        u = min(max(u, 0), GN - 1);
        float e = el[u * 4 + h] + erv;
        e = e > 0.f ? e : 0.2f * e;
        float w = (jl < chn) ? __expf(fminf(e, 60.f)) : 0.f;
        s_part += w;
        // ---- gather phase: batches of 8 edges; all loads independent, issued together ----
#pragma unroll
        for (int jb = 0; jb < 16; jb += 8) {
            if (jb >= chn) break;  // wave-uniform
            unsigned pq[8];
            float wqv[8];
            unsigned pbq[8];
#pragma unroll
            for (int q = 0; q < 8; q++) {
                int j4 = (jb + q) * 4;
                int us = __builtin_amdgcn_readlane(u, j4);  // SGPR base, no LDS-pipe dep
                pq[q] = *(const unsigned*)(ft + (size_t)us * FTOT + c0);
                wqv[q] = __shfl(w, j4 + h0);
                if constexpr (FINAL) {
                    if (lane < 16) {
                        pbq[q] = *(const unsigned*)(ft + (size_t)us * FTOT + 128 + c0);
                    }
                }
            }
#pragma unroll
            for (int q = 0; q < 8; q++) {
                a0 += wqv[q] * lo16(pq[q]);
                a1 += wqv[q] * hi16(pq[q]);
                if constexpr (FINAL) {
                    // pair1 cols 128..159 are head 3: uniform weight via readlane
                    float wb = __uint_as_float(
                        __builtin_amdgcn_readlane(__float_as_uint(w), (jb + q) * 4 + 3));
                    if (lane < 16) {
                        a2 += wb * lo16(pbq[q]);
                        a3 += wb * hi16(pbq[q]);
                    }
                }
            }
        }
    }

    // ---- s reduction: butterfly over slot bits (head preserved in lane&3) ----
#pragma unroll
    for (int off = 4; off < 64; off <<= 1) s_part += __shfl_xor(s_part, off);
    float s0 = __shfl(s_part, h0);  // lane h0 (0..3) holds head-h0 total

    float r0 = (s0 > 0.f) ? a0 / s0 : 0.f;
    float r1 = (s0 > 0.f) ? a1 / s0 : 0.f;

    if constexpr (!FINAL) {
        unsigned pk = *(const unsigned*)(skip_pre + (size_t)v * FTOT + c0);
        float o0 = r0 + ldx(bias, c0, m) + lo16(pk);
        float o1 = r1 + ldx(bias, c0 + 1, m) + hi16(pk);
        unsigned po = ((unsigned)f2bfu(guard_finite(o1)) << 16) |
                      (unsigned)f2bfu(guard_finite(o0));
        *(unsigned*)(out + (size_t)v * FTOT + c0) = po;
    } else {
        float s3 = __shfl(s_part, 3);
        float o0 = r0 + ldx(bias, c0, m);
        float o1 = r1 + ldx(bias, c0 + 1, m);
        float r2 = (s3 > 0.f) ? a2 / s3 : 0.f;
        float r3 = (s3 > 0.f) ? a3 / s3 : 0.f;
        int cb0 = 128 + c0;  // meaningful for lane<16 only
        float o2 = r2 + ldx(bias, (cb0 < FTOT) ? cb0 : 0, m);
        float o3 = r3 + ldx(bias, (cb0 + 1 < FTOT) ? cb0 + 1 : 1, m);

        // head-average: lane t<40 needs cols t, t+40, t+80, t+120 (all parity t&1)
        int t = lane;
        bool od = (t & 1);
        int sA = (t >> 1) & 63;
        int sB = ((t + 40) >> 1) & 63;
        int sC = ((t + 80) >> 1) & 63;
        int sD1 = ((t + 120) >> 1) & 63;          // valid when t<8 (col<128, from o0/o1)
        int sD2 = ((t >= 8 ? t - 8 : 0) >> 1);    // valid when t>=8 (col>=128, from o2/o3)
        float vA0 = __shfl(o0, sA), vA1 = __shfl(o1, sA);
        float vB0 = __shfl(o0, sB), vB1 = __shfl(o1, sB);
        float vC0 = __shfl(o0, sC), vC1 = __shfl(o1, sC);
        float vD10 = __shfl(o0, sD1), vD11 = __shfl(o1, sD1);
        float vD20 = __shfl(o2, sD2), vD21 = __shfl(o3, sD2);
        float vA = od ? vA1 : vA0;
        float vB = od ? vB1 : vB0;
        float vC = od ? vC1 : vC0;
        float vD = (t < 8) ? (od ? vD11 : vD10) : (od ? vD21 : vD20);

        float x = -3.0e38f;
        if (t < 40) {
            float sm = __bfloat162float(((const bf16*)h_in)[(size_t)v * 128 + t]);
            x = 0.25f * (vA + vB + vC + vD) + sm + ldx(bias_last, t, m);
        }
        float mx = x;
#pragma unroll
        for (int off = 1; off < 64; off <<= 1) mx = fmaxf(mx, __shfl_xor(mx, off));
        float ex = (t < 40) ? __expf(x - mx) : 0.f;
        float sum = ex;
#pragma unroll
        for (int off = 1; off < 64; off <<= 1) sum += __shfl_xor(sum, off);
        if (t < 40) stx(fout, (size_t)v * 40 + t, m, guard_finite(x - mx - __logf(sum)));
    }
}

// ---------------- BatchNorm (+ ReLU) on bf16 [N,128] ----------------
__global__ void bn_stats(const bf16* __restrict__ x, float* __restrict__ gsum,
                         float* __restrict__ gsq, int n) {
    int c = threadIdx.x;  // 128
    int rows_per_block = (n + gridDim.x - 1) / gridDim.x;
    int r0 = blockIdx.x * rows_per_block;
    int r1 = min(n, r0 + rows_per_block);
    float s = 0.f, q = 0.f;
    for (int r = r0; r < r1; r++) {
        float v = __bfloat162float(x[(size_t)r * 128 + c]);
        s += v;
        q += v * v;
    }
    atomicAdd(&gsum[c], s);
    atomicAdd(&gsq[c], q);
}

__global__ void bn_apply(bf16* __restrict__ x, const float* __restrict__ gsum,
                         const float* __restrict__ gsq, const void* __restrict__ g,
                         const void* __restrict__ be, int n, const int* __restrict__ flag) {
    int m = (*flag != 0) ? 1 : 0;
    int gid = blockIdx.x * blockDim.x + threadIdx.x;
    if (gid >= n * 128) return;
    int c = gid & 127;
    float inv_n = 1.f / (float)n;
    float mu = gsum[c] * inv_n;
    float var = gsq[c] * inv_n - mu * mu;
    float y = (__bfloat162float(x[gid]) - mu) * rsqrtf(fmaxf(var, 0.f) + 1e-5f) * ldx(g, c, m) +
              ldx(be, c, m);
    x[gid] = __float2bfloat16(y > 0.f ? y : 0.f);
}

extern "C" void kernel_launch(void* const* d_in, const int* in_sizes, int n_in,
                              void* d_out, int out_size, void* d_ws, size_t ws_size,
                              hipStream_t stream) {
    const void* feat = d_in[0];
    const int* src = (const int*)d_in[1];
    const int* dst = (const int*)d_in[2];
    const void* w_fc0 = d_in[3];
    const void* al0 = d_in[4];
    const void* ar0 = d_in[5];
    const void* b0 = d_in[6];
    const void* w_lin0 = d_in[7];
    const void* g0 = d_in[8];
    const void* be0 = d_in[9];
    const void* w_fc1 = d_in[10];
    const void* al1 = d_in[11];
    const void* ar1 = d_in[12];
    const void* b1 = d_in[13];
    const void* w_lin1 = d_in[14];
    const void* g1 = d_in[15];
    const void* be1 = d_in[16];
    const void* w_fc2 = d_in[17];
    const void* al2 = d_in[18];
    const void* ar2 = d_in[19];
    const void* b2 = d_in[20];
    const void* w_lin2 = d_in[21];
    const void* bias_last = d_in[22];

    // ---- workspace guard: total need ~34.5 MB ----
    if (ws_size < 35000000) {
        sentinel_kernel<<<(out_size + 255) / 256, 256, 0, stream>>>((unsigned short*)d_out,
                                                                    out_size);
        return;
    }

    char* p = (char*)d_ws;
    auto alloc = [&](size_t bytes) {
        char* r = p;
        p += (bytes + 255) & ~(size_t)255;
        return r;
    };
    bf16* ftb = (bf16*)alloc((size_t)GN * 160 * 2);   // 16.0 MB
    bf16* hbuf = (bf16*)alloc((size_t)GN * 128 * 2);  // 12.8 MB
    float* elb = (float*)alloc((size_t)GN * 4 * 4);   // 0.8 MB
    float* erb = (float*)alloc((size_t)GN * 4 * 4);   // 0.8 MB
    int* indptr = (int*)alloc((size_t)(GN + 1) * 4);
    int* cursor = (int*)alloc((size_t)GN * 4);
    int* bsum = (int*)alloc(256 * 4);                 // block sums for 3-pass scan
    unsigned short* wmt = (unsigned short*)alloc(48 * 128 * 2);  // 12.3 KB
    char* zbase = p;  // ---- zero-initialized region ----
    int* deg = (int*)alloc((size_t)GN * 4);
    int* csr = (int*)alloc((size_t)GE * 4);  // 3.2 MB
    float* gs0 = (float*)alloc(128 * 4);
    float* gq0 = (float*)alloc(128 * 4);
    float* gs1 = (float*)alloc(128 * 4);
    float* gq1 = (float*)alloc(128 * 4);
    int* flag = (int*)alloc(4);
    hipMemsetAsync(zbase, 0, (size_t)(p - zbase), stream);

    detect_kernel<<<1, 256, 0, stream>>>((const unsigned short*)feat, flag);

    // CSR build + w-mean precompute (independent, early)
    const int NB = (GN + 255) / 256;  // 196 scan blocks
    count_kernel<<<(GE + 255) / 256, 256, 0, stream>>>(dst, deg, GE);
    scan1_kernel<<<NB, 256, 0, stream>>>(deg, cursor, bsum, GN);   // cursor = per-block incl scan
    scan2_kernel<<<1, 256, 0, stream>>>(bsum, NB);                 // bsum = exclusive block offs
    scan3_kernel<<<NB, 256, 0, stream>>>(deg, cursor, bsum, indptr, cursor, GN);
    scatter_kernel<<<(GE + 255) / 256, 256, 0, stream>>>(src, dst, cursor, csr, GE);
    wmean_kernel<<<24, 256, 0, stream>>>(w_lin2, wmt, flag);

    dim3 g3(782, 3);
    const int AGGB = (GN + 3) / 4;  // 12500 blocks, 4 waves (nodes) each

    // ----- Layer 0 (fused: ftb = feat@w_fc0, hbuf = feat@w_lin0; feat read once) -----
    gemm_dual<<<782, 256, 0, stream>>>(feat, 1, w_fc0, w_lin0, ftb, hbuf, GN, flag);
    elr_kernel<<<(GN * 4 + 255) / 256, 256, 0, stream>>>(ftb, al0, ar0, elb, erb, GN, 32, flag);
    agg_wave<128, false><<<AGGB, 256, 0, stream>>>(ftb, elb, erb, indptr, csr, b0, nullptr,
                                                   hbuf, hbuf, nullptr, nullptr, flag);
    bn_stats<<<256, 128, 0, stream>>>(hbuf, gs0, gq0, GN);
    bn_apply<<<(GN * 128 + 255) / 256, 256, 0, stream>>>(hbuf, gs0, gq0, g0, be0, GN, flag);

    // ----- Layer 1 (fused: ftb = h1@w_fc1, hbuf <- h1@w_lin1 in-place) -----
    gemm_dual<<<782, 256, 0, stream>>>(hbuf, 0, w_fc1, w_lin1, ftb, hbuf, GN, flag);
    elr_kernel<<<(GN * 4 + 255) / 256, 256, 0, stream>>>(ftb, al1, ar1, elb, erb, GN, 32, flag);
    agg_wave<128, false><<<AGGB, 256, 0, stream>>>(ftb, elb, erb, indptr, csr, b1, nullptr,
                                                   hbuf, hbuf, nullptr, nullptr, flag);
    bn_stats<<<256, 128, 0, stream>>>(hbuf, gs1, gq1, GN);
    bn_apply<<<(GN * 128 + 255) / 256, 256, 0, stream>>>(hbuf, gs1, gq1, g1, be1, GN, flag);

    // ----- Layer 2 (final) -----
    gemm_tile<<<g3, 256, 0, stream>>>(hbuf, 0, w_fc2, ftb, GN, 160, flag);
    elr_kernel<<<(GN * 4 + 255) / 256, 256, 0, stream>>>(ftb, al2, ar2, elb, erb, GN, 40, flag);
    skipmean_inplace<<<782, 256, 0, stream>>>(hbuf, wmt, GN);  // hbuf[:,0:40] <- h2 @ wmean
    agg_wave<160, true><<<AGGB, 256, 0, stream>>>(ftb, elb, erb, indptr, csr, b2, hbuf,
                                                  nullptr, nullptr, bias_last, d_out, flag);
}

// Round 4
// 592.407 us; speedup vs baseline: 1.5280x; 1.2234x over previous
//
#include <hip/hip_runtime.h>
#include <hip/hip_bf16.h>

#define GN 50000
#define GE 800000
#define GH 4
#define GFH 32
#define GC 40
#define GIN 128

typedef __hip_bfloat16 bf16;
typedef __attribute__((ext_vector_type(8))) short bf16x8;
typedef __attribute__((ext_vector_type(4))) float f32x4;

// mode m: 0 = tensor stored as bf16, 1 = stored as fp32
static __device__ __forceinline__ float ldx(const void* p, size_t i, int m) {
    if (m) return ((const float*)p)[i];
    return __bfloat162float(((const bf16*)p)[i]);
}
static __device__ __forceinline__ void stx(void* p, size_t i, int m, float v) {
    if (m) ((float*)p)[i] = v;
    else ((bf16*)p)[i] = __float2bfloat16(v);
}
static __device__ __forceinline__ unsigned short f2bfu(float v) {
    union { bf16 b; unsigned short u; } cv;
    cv.b = __float2bfloat16(v);
    return cv.u;
}
static __device__ __forceinline__ float lo16(unsigned u) { return __uint_as_float(u << 16); }
static __device__ __forceinline__ float hi16(unsigned u) { return __uint_as_float(u & 0xFFFF0000u); }
static __device__ __forceinline__ float guard_finite(float v) {
    if (!(v == v) || fabsf(v) > 1e30f) return 0.f;
    return v;
}

// ---------------- dtype probe: fp32 misread as bf16 shows wild exponents ----------------
__global__ void detect_kernel(const unsigned short* __restrict__ f, int* __restrict__ flag) {
    int t = threadIdx.x;  // 256
    unsigned short u = f[t];
    int e = (u >> 7) & 0xFF;
    if (e >= 0x8E) atomicAdd(flag, 1);  // |val| >= 2^15 or inf/nan -> not sane bf16 data
}

__global__ void sentinel_kernel(unsigned short* __restrict__ o, int n) {
    int i = blockIdx.x * blockDim.x + threadIdx.x;
    if (i < n) o[i] = 0x3F80;  // bf16 1.0
}

// ---------------- CSR build ----------------
__global__ void count_kernel(const int* __restrict__ dst, int* __restrict__ deg, int n) {
    int e = blockIdx.x * blockDim.x + threadIdx.x;
    if (e < n) {
        int d = dst[e];
        if (d >= 0 && d < GN) atomicAdd(&deg[d], 1);
    }
}

// ---- 3-pass device-wide scan ----
__global__ void scan1_kernel(const int* __restrict__ deg, int* __restrict__ tmp,
                             int* __restrict__ bsum, int n) {
    int tid = threadIdx.x;
    int i = blockIdx.x * 256 + tid;
    int v = (i < n) ? deg[i] : 0;
    int lane = tid & 63, wid = tid >> 6;
    int s = v;
#pragma unroll
    for (int off = 1; off < 64; off <<= 1) {
        int u = __shfl_up(s, off);
        if (lane >= off) s += u;
    }
    __shared__ int wsum[4];
    if (lane == 63) wsum[wid] = s;
    __syncthreads();
    int woff = 0;
#pragma unroll
    for (int w = 0; w < 4; w++) woff += (w < wid) ? wsum[w] : 0;
    int incl = s + woff;
    if (i < n) tmp[i] = incl;
    if (tid == 255) bsum[blockIdx.x] = incl;  // block total (zeros padded past n)
}

__global__ void scan2_kernel(int* __restrict__ bsum, int nb) {
    int tid = threadIdx.x;
    int v = (tid < nb) ? bsum[tid] : 0;
    int lane = tid & 63, wid = tid >> 6;
    int s = v;
#pragma unroll
    for (int off = 1; off < 64; off <<= 1) {
        int u = __shfl_up(s, off);
        if (lane >= off) s += u;
    }
    __shared__ int wsum[4];
    if (lane == 63) wsum[wid] = s;
    __syncthreads();
    int woff = 0;
#pragma unroll
    for (int w = 0; w < 4; w++) woff += (w < wid) ? wsum[w] : 0;
    if (tid < nb) bsum[tid] = s + woff - v;  // exclusive
}

__global__ void scan3_kernel(const int* __restrict__ deg, const int* __restrict__ tmp,
                             const int* __restrict__ bsum, int* __restrict__ indptr,
                             int* __restrict__ cursor, int n) {
    int i = blockIdx.x * 256 + threadIdx.x;
    if (i < n) {
        int incl = tmp[i] + bsum[blockIdx.x];
        indptr[i + 1] = incl;
        cursor[i] = incl - deg[i];
        if (i == 0) indptr[0] = 0;
    }
}

__global__ void scatter_kernel(const int* __restrict__ src, const int* __restrict__ dst,
                               int* __restrict__ cursor, int* __restrict__ csr_src, int n) {
    int e = blockIdx.x * blockDim.x + threadIdx.x;
    if (e < n) {
        int d = dst[e];
        if (d < 0 || d >= GN) return;
        int p = atomicAdd(&cursor[d], 1);
        if (p >= 0 && p < GE) csr_src[p] = src[e];
    }
}

// ---------------- w-mean: wmt[c][128] (c<48, zero-pad c>=40) = mean_h w_lin2[k][h*40+c] ----------------
__global__ void wmean_kernel(const void* __restrict__ w, unsigned short* __restrict__ wmt,
                             const int* __restrict__ flag) {
    int m = (*flag != 0) ? 1 : 0;
    int idx = blockIdx.x * blockDim.x + threadIdx.x;
    if (idx < 48 * 128) {
        int c = idx >> 7, k = idx & 127;
        float s = 0.f;
        if (c < 40) {
            s = 0.25f * (ldx(w, (size_t)k * 160 + c, m) + ldx(w, (size_t)k * 160 + 40 + c, m) +
                         ldx(w, (size_t)k * 160 + 80 + c, m) + ldx(w, (size_t)k * 160 + 120 + c, m));
        }
        wmt[c * 128 + k] = f2bfu(s);
    }
}

// ---------------- weight transpose: WT[c][128] = bf16(W[k][c]) ----------------
// coalesced reads (consecutive idx -> consecutive c in W's row-major layout), scattered 2B writes
__global__ void wtrans_kernel(const void* __restrict__ W, unsigned short* __restrict__ WT,
                              int M, const int* __restrict__ flag) {
    int m = (*flag != 0) ? 1 : 0;
    int idx = blockIdx.x * blockDim.x + threadIdx.x;
    if (idx < M * 128) {
        int c = idx % M, k = idx / M;
        WT[(size_t)c * 128 + k] = f2bfu(ldx(W, (size_t)k * M + c, m));
    }
}

// ---------------- MFMA GEMM: Y[N,M](bf16) = X[N,128] @ WT^T  (WT: [M][128] pre-transposed) ----------------
__global__ __launch_bounds__(256) void gemm_tile(const bf16* __restrict__ X,
                                                 const unsigned short* __restrict__ WT,
                                                 bf16* __restrict__ Y, int nrows, int M) {
    constexpr int LDX = 136;
    __shared__ unsigned short Xs[64 * LDX];  // [r][k]
    __shared__ unsigned short Wt[64 * LDX];  // [c][k]
    int tid = threadIdx.x;
    int rb = blockIdx.x * 64, cb = blockIdx.y * 64;

#pragma unroll
    for (int it = 0; it < 4; it++) {  // 64x128 bf16, uint4 = 8 elems
        int e = (tid + it * 256) * 8;
        int r = e >> 7, k0 = e & 127;
        int row = rb + r;
        uint4 v = {0u, 0u, 0u, 0u};
        if (row < nrows) v = *(const uint4*)((const unsigned short*)X + (size_t)row * 128 + k0);
        *(uint4*)&Xs[r * LDX + k0] = v;
    }
#pragma unroll
    for (int it = 0; it < 4; it++) {  // 64x128 weight rows [cb..cb+64)
        int e = (tid + it * 256) * 8;
        int cl = e >> 7, k0 = e & 127;
        int c = cb + cl;
        uint4 v = {0u, 0u, 0u, 0u};
        if (c < M) v = *(const uint4*)(WT + (size_t)c * 128 + k0);
        *(uint4*)&Wt[cl * LDX + k0] = v;
    }
    __syncthreads();

    int wave = tid >> 6, lane = tid & 63;
    int lr = lane & 15, quad = lane >> 4;
    int mrow = wave * 16 + lr;

    f32x4 acc[4] = {};
    for (int kk = 0; kk < 128; kk += 32) {
        bf16x8 a = *(const bf16x8*)&Xs[mrow * LDX + kk + quad * 8];
#pragma unroll
        for (int nt = 0; nt < 4; nt++) {
            bf16x8 b = *(const bf16x8*)&Wt[(nt * 16 + lr) * LDX + kk + quad * 8];
            acc[nt] = __builtin_amdgcn_mfma_f32_16x16x32_bf16(a, b, acc[nt], 0, 0, 0);
        }
    }

    int drow = rb + wave * 16 + quad * 4;
#pragma unroll
    for (int nt = 0; nt < 4; nt++) {
        int col = cb + nt * 16 + lr;
#pragma unroll
        for (int i = 0; i < 4; i++) {
            int row = drow + i;
            if (row < nrows && col < M) Y[(size_t)row * M + col] = __float2bfloat16(acc[nt][i]);
        }
    }
}

// ---------------- MFMA dual GEMM: Y1 = X@WT1^T, Y2 = X@WT2^T (both 128 cols); X staged once ----------------
// Y2 may alias X (in-place): each block reads/writes only its own 64 rows.
__global__ __launch_bounds__(256) void gemm_dual(const void* __restrict__ X, int xext,
                                                 const unsigned short* __restrict__ WT1,
                                                 const unsigned short* __restrict__ WT2,
                                                 bf16* __restrict__ Y1, bf16* __restrict__ Y2,
                                                 int nrows, const int* __restrict__ flag) {
    constexpr int LDX = 136;
    __shared__ unsigned short Xs[64 * LDX];   // [r][k]
    __shared__ unsigned short Wt[128 * LDX];  // [c][k], reused for W1 then W2
    int xfp32 = xext && (*flag != 0);
    int tid = threadIdx.x;
    int rb = blockIdx.x * 64;

    if (xfp32) {
#pragma unroll
        for (int it = 0; it < 8; it++) {  // float4 = 4 elems
            int e = (tid + it * 256) * 4;
            int r = e >> 7, k0 = e & 127;
            int row = rb + r;
            float4 v = {0.f, 0.f, 0.f, 0.f};
            if (row < nrows) v = *(const float4*)((const float*)X + (size_t)row * 128 + k0);
            unsigned lo = (unsigned)f2bfu(v.x) | ((unsigned)f2bfu(v.y) << 16);
            unsigned hi = (unsigned)f2bfu(v.z) | ((unsigned)f2bfu(v.w) << 16);
            uint2 o = {lo, hi};
            *(uint2*)&Xs[r * LDX + k0] = o;
        }
    } else {
#pragma unroll
        for (int it = 0; it < 4; it++) {  // uint4 = 8 bf16
            int e = (tid + it * 256) * 8;
            int r = e >> 7, k0 = e & 127;
            int row = rb + r;
            uint4 v = {0u, 0u, 0u, 0u};
            if (row < nrows) v = *(const uint4*)((const unsigned short*)X + (size_t)row * 128 + k0);
            *(uint4*)&Xs[r * LDX + k0] = v;
        }
    }
#pragma unroll
    for (int it = 0; it < 8; it++) {  // 128x128 weight tile
        int e = (tid + it * 256) * 8;
        int c = e >> 7, k0 = e & 127;
        *(uint4*)&Wt[c * LDX + k0] = *(const uint4*)(WT1 + (size_t)c * 128 + k0);
    }
    __syncthreads();

    int wave = tid >> 6, lane = tid & 63;
    int lr = lane & 15, quad = lane >> 4;
    int mrow = wave * 16 + lr;
    int drow = rb + wave * 16 + quad * 4;

    {
        f32x4 acc[8] = {};
        for (int kk = 0; kk < 128; kk += 32) {
            bf16x8 a = *(const bf16x8*)&Xs[mrow * LDX + kk + quad * 8];
#pragma unroll
            for (int nt = 0; nt < 8; nt++) {
                bf16x8 b = *(const bf16x8*)&Wt[(nt * 16 + lr) * LDX + kk + quad * 8];
                acc[nt] = __builtin_amdgcn_mfma_f32_16x16x32_bf16(a, b, acc[nt], 0, 0, 0);
            }
        }
#pragma unroll
        for (int nt = 0; nt < 8; nt++) {
            int col = nt * 16 + lr;
#pragma unroll
            for (int i = 0; i < 4; i++) {
                int row = drow + i;
                if (row < nrows) Y1[(size_t)row * 128 + col] = __float2bfloat16(acc[nt][i]);
            }
        }
    }
    __syncthreads();  // all waves done reading W1 tile
#pragma unroll
    for (int it = 0; it < 8; it++) {
        int e = (tid + it * 256) * 8;
        int c = e >> 7, k0 = e & 127;
        *(uint4*)&Wt[c * LDX + k0] = *(const uint4*)(WT2 + (size_t)c * 128 + k0);
    }
    __syncthreads();
    {
        f32x4 acc[8] = {};
        for (int kk = 0; kk < 128; kk += 32) {
            bf16x8 a = *(const bf16x8*)&Xs[mrow * LDX + kk + quad * 8];
#pragma unroll
            for (int nt = 0; nt < 8; nt++) {
                bf16x8 b = *(const bf16x8*)&Wt[(nt * 16 + lr) * LDX + kk + quad * 8];
                acc[nt] = __builtin_amdgcn_mfma_f32_16x16x32_bf16(a, b, acc[nt], 0, 0, 0);
            }
        }
#pragma unroll
        for (int nt = 0; nt < 8; nt++) {
            int col = nt * 16 + lr;
#pragma unroll
            for (int i = 0; i < 4; i++) {
                int row = drow + i;
                if (row < nrows) Y2[(size_t)row * 128 + col] = __float2bfloat16(acc[nt][i]);
            }
        }
    }
}

// ---------------- skipmean in-place: X[:,0:40] <- X @ wmt^T (wmt: [48][128]) ----------------
__global__ __launch_bounds__(256) void skipmean_inplace(bf16* __restrict__ X,
                                                        const unsigned short* __restrict__ wmt,
                                                        int nrows) {
    constexpr int LDX = 136;
    __shared__ unsigned short Xs[64 * LDX];  // [r][k]
    __shared__ unsigned short Wt[48 * LDX];  // [c][k]
    int tid = threadIdx.x;
    int rb = blockIdx.x * 64;

#pragma unroll
    for (int it = 0; it < 4; it++) {
        int e = (tid + it * 256) * 8;
        int r = e >> 7, k0 = e & 127;
        int row = rb + r;
        uint4 v = {0u, 0u, 0u, 0u};
        if (row < nrows) v = *(const uint4*)((const unsigned short*)X + (size_t)row * 128 + k0);
        *(uint4*)&Xs[r * LDX + k0] = v;
    }
#pragma unroll
    for (int it = 0; it < 3; it++) {  // 48x128
        int e = (tid + it * 256) * 8;
        int c = e >> 7, k0 = e & 127;
        *(uint4*)&Wt[c * LDX + k0] = *(const uint4*)(wmt + (size_t)c * 128 + k0);
    }
    __syncthreads();

    int wave = tid >> 6, lane = tid & 63;
    int lr = lane & 15, quad = lane >> 4;
    int mrow = wave * 16 + lr;

    f32x4 acc[3] = {};
    for (int kk = 0; kk < 128; kk += 32) {
        bf16x8 a = *(const bf16x8*)&Xs[mrow * LDX + kk + quad * 8];
#pragma unroll
        for (int nt = 0; nt < 3; nt++) {
            bf16x8 b = *(const bf16x8*)&Wt[(nt * 16 + lr) * LDX + kk + quad * 8];
            acc[nt] = __builtin_amdgcn_mfma_f32_16x16x32_bf16(a, b, acc[nt], 0, 0, 0);
        }
    }

    int drow = rb + wave * 16 + quad * 4;
#pragma unroll
    for (int nt = 0; nt < 3; nt++) {
        int col = nt * 16 + lr;
        if (col < 40) {
#pragma unroll
            for (int i = 0; i < 4; i++) {
                int row = drow + i;
                if (row < nrows) X[(size_t)row * 128 + col] = __float2bfloat16(acc[nt][i]);
            }
        }
    }
}

// ---------------- el/er: [N,H] dot over F (vectorized bf16x8 loads) ----------------
__global__ void elr_kernel(const bf16* __restrict__ ft, const void* __restrict__ al,
                           const void* __restrict__ ar, float* __restrict__ el,
                           float* __restrict__ er, int n, int F, const int* __restrict__ flag) {
    int m = (*flag != 0) ? 1 : 0;
    int gid = blockIdx.x * blockDim.x + threadIdx.x;
    if (gid >= n * 4) return;
    int nid = gid >> 2, h = gid & 3;
    const bf16* f = ft + (size_t)nid * (4 * F) + h * F;
    float sl = 0.f, sr = 0.f;
    for (int i0 = 0; i0 < F; i0 += 8) {
        bf16x8 v8 = *(const bf16x8*)(f + i0);
#pragma unroll
        for (int i = 0; i < 8; i++) {
            float v = __uint_as_float(((unsigned)(unsigned short)v8[i]) << 16);
            sl += v * ldx(al, h * F + i0 + i, m);
            sr += v * ldx(ar, h * F + i0 + i, m);
        }
    }
    el[gid] = sl;
    er[gid] = sr;
}

// ---------------- per-dst softmax + aggregation: ONE WAVE PER NODE, zero barriers ----------------
template <int FTOT, bool FINAL>
__global__ __launch_bounds__(256) void agg_wave(
    const bf16* __restrict__ ft, const float* __restrict__ el, const float* __restrict__ er,
    const int* __restrict__ indptr, const int* __restrict__ csr_src,
    const void* __restrict__ bias, const void* __restrict__ h_in,
    const bf16* __restrict__ skip_pre, bf16* __restrict__ out,
    const void* __restrict__ bias_last, void* __restrict__ fout,
    const int* __restrict__ flag) {
    constexpr int HF = FTOT / 4;
    int m = (*flag != 0) ? 1 : 0;
    int lane = threadIdx.x & 63;
    int v = blockIdx.x * 4 + (threadIdx.x >> 6);
    if (v >= GN) return;
    int beg = indptr[v], end = indptr[v + 1];
    beg = max(0, min(beg, GE));
    end = max(beg, min(end, GE));

    int h = lane & 3, jl = lane >> 2;  // weight-phase mapping: edge slot jl, head h
    int c0 = 2 * lane;                 // gather-phase feature pair
    int h0 = c0 / HF;
    float erv = er[v * 4 + h];

    float a0 = 0.f, a1 = 0.f, a2 = 0.f, a3 = 0.f;
    float s_part = 0.f;

    for (int cb = beg; cb < end; cb += 16) {
        int chn = end - cb;
        chn = chn < 16 ? chn : 16;
        // ---- weight phase (this chunk's 16 edges) ----
        int u = csr_src[cb + (jl < chn ? jl : chn - 1)];
        u = min(max(u, 0), GN - 1);
        float e = el[u * 4 + h] + erv;
        e = e > 0.f ? e : 0.2f * e;
        float w = (jl < chn) ? __expf(fminf(e, 60.f)) : 0.f;
        s_part += w;
        // ---- gather phase: batches of 8 edges; all loads independent, issued together ----
#pragma unroll
        for (int jb = 0; jb < 16; jb += 8) {
            if (jb >= chn) break;  // wave-uniform
            unsigned pq[8];
            float wqv[8];
            unsigned pbq[8];
#pragma unroll
            for (int q = 0; q < 8; q++) {
                int j4 = (jb + q) * 4;
                int us = __builtin_amdgcn_readlane(u, j4);  // SGPR base, no LDS-pipe dep
                pq[q] = *(const unsigned*)(ft + (size_t)us * FTOT + c0);
                wqv[q] = __shfl(w, j4 + h0);
                if constexpr (FINAL) {
                    if (lane < 16) {
                        pbq[q] = *(const unsigned*)(ft + (size_t)us * FTOT + 128 + c0);
                    }
                }
            }
#pragma unroll
            for (int q = 0; q < 8; q++) {
                a0 += wqv[q] * lo16(pq[q]);
                a1 += wqv[q] * hi16(pq[q]);
                if constexpr (FINAL) {
                    // pair1 cols 128..159 are head 3: uniform weight via readlane
                    float wb = __uint_as_float(
                        __builtin_amdgcn_readlane(__float_as_uint(w), (jb + q) * 4 + 3));
                    if (lane < 16) {
                        a2 += wb * lo16(pbq[q]);
                        a3 += wb * hi16(pbq[q]);
                    }
                }
            }
        }
    }

    // ---- s reduction: butterfly over slot bits (head preserved in lane&3) ----
#pragma unroll
    for (int off = 4; off < 64; off <<= 1) s_part += __shfl_xor(s_part, off);
    float s0 = __shfl(s_part, h0);  // lane h0 (0..3) holds head-h0 total

    float r0 = (s0 > 0.f) ? a0 / s0 : 0.f;
    float r1 = (s0 > 0.f) ? a1 / s0 : 0.f;

    if constexpr (!FINAL) {
        unsigned pk = *(const unsigned*)(skip_pre + (size_t)v * FTOT + c0);
        float o0 = r0 + ldx(bias, c0, m) + lo16(pk);
        float o1 = r1 + ldx(bias, c0 + 1, m) + hi16(pk);
        unsigned po = ((unsigned)f2bfu(guard_finite(o1)) << 16) |
                      (unsigned)f2bfu(guard_finite(o0));
        *(unsigned*)(out + (size_t)v * FTOT + c0) = po;
    } else {
        float s3 = __shfl(s_part, 3);
        float o0 = r0 + ldx(bias, c0, m);
        float o1 = r1 + ldx(bias, c0 + 1, m);
        float r2 = (s3 > 0.f) ? a2 / s3 : 0.f;
        float r3 = (s3 > 0.f) ? a3 / s3 : 0.f;
        int cb0 = 128 + c0;  // meaningful for lane<16 only
        float o2 = r2 + ldx(bias, (cb0 < FTOT) ? cb0 : 0, m);
        float o3 = r3 + ldx(bias, (cb0 + 1 < FTOT) ? cb0 + 1 : 1, m);

        // head-average: lane t<40 needs cols t, t+40, t+80, t+120 (all parity t&1)
        int t = lane;
        bool od = (t & 1);
        int sA = (t >> 1) & 63;
        int sB = ((t + 40) >> 1) & 63;
        int sC = ((t + 80) >> 1) & 63;
        int sD1 = ((t + 120) >> 1) & 63;          // valid when t<8 (col<128, from o0/o1)
        int sD2 = ((t >= 8 ? t - 8 : 0) >> 1);    // valid when t>=8 (col>=128, from o2/o3)
        float vA0 = __shfl(o0, sA), vA1 = __shfl(o1, sA);
        float vB0 = __shfl(o0, sB), vB1 = __shfl(o1, sB);
        float vC0 = __shfl(o0, sC), vC1 = __shfl(o1, sC);
        float vD10 = __shfl(o0, sD1), vD11 = __shfl(o1, sD1);
        float vD20 = __shfl(o2, sD2), vD21 = __shfl(o3, sD2);
        float vA = od ? vA1 : vA0;
        float vB = od ? vB1 : vB0;
        float vC = od ? vC1 : vC0;
        float vD = (t < 8) ? (od ? vD11 : vD10) : (od ? vD21 : vD20);

        float x = -3.0e38f;
        if (t < 40) {
            float sm = __bfloat162float(((const bf16*)h_in)[(size_t)v * 128 + t]);
            x = 0.25f * (vA + vB + vC + vD) + sm + ldx(bias_last, t, m);
        }
        float mx = x;
#pragma unroll
        for (int off = 1; off < 64; off <<= 1) mx = fmaxf(mx, __shfl_xor(mx, off));
        float ex = (t < 40) ? __expf(x - mx) : 0.f;
        float sum = ex;
#pragma unroll
        for (int off = 1; off < 64; off <<= 1) sum += __shfl_xor(sum, off);
        if (t < 40) stx(fout, (size_t)v * 40 + t, m, guard_finite(x - mx - __logf(sum)));
    }
}

// ---------------- BatchNorm (+ ReLU) on bf16 [N,128] ----------------
__global__ void bn_stats(const bf16* __restrict__ x, float* __restrict__ gsum,
                         float* __restrict__ gsq, int n) {
    int c = threadIdx.x;  // 128
    int rows_per_block = (n + gridDim.x - 1) / gridDim.x;
    int r0 = blockIdx.x * rows_per_block;
    int r1 = min(n, r0 + rows_per_block);
    float s = 0.f, q = 0.f;
    for (int r = r0; r < r1; r++) {
        float v = __bfloat162float(x[(size_t)r * 128 + c]);
        s += v;
        q += v * v;
    }
    atomicAdd(&gsum[c], s);
    atomicAdd(&gsq[c], q);
}

// vectorized: 8 bf16 per thread (uint4)
__global__ void bn_apply(bf16* __restrict__ x, const float* __restrict__ gsum,
                         const float* __restrict__ gsq, const void* __restrict__ g,
                         const void* __restrict__ be, int n, const int* __restrict__ flag) {
    int m = (*flag != 0) ? 1 : 0;
    int gid8 = blockIdx.x * blockDim.x + threadIdx.x;
    if (gid8 >= n * 16) return;  // n*128/8
    int c0 = (gid8 & 15) * 8;
    float inv_n = 1.f / (float)n;
    uint4 v = *(uint4*)((unsigned short*)x + (size_t)gid8 * 8);
    unsigned* pw = (unsigned*)&v;
#pragma unroll
    for (int i = 0; i < 4; i++) {
        int c = c0 + 2 * i;
        float mu0 = gsum[c] * inv_n, mu1 = gsum[c + 1] * inv_n;
        float var0 = gsq[c] * inv_n - mu0 * mu0, var1 = gsq[c + 1] * inv_n - mu1 * mu1;
        float y0 = (lo16(pw[i]) - mu0) * rsqrtf(fmaxf(var0, 0.f) + 1e-5f) * ldx(g, c, m) +
                   ldx(be, c, m);
        float y1 = (hi16(pw[i]) - mu1) * rsqrtf(fmaxf(var1, 0.f) + 1e-5f) * ldx(g, c + 1, m) +
                   ldx(be, c + 1, m);
        y0 = y0 > 0.f ? y0 : 0.f;
        y1 = y1 > 0.f ? y1 : 0.f;
        pw[i] = (unsigned)f2bfu(y0) | ((unsigned)f2bfu(y1) << 16);
    }
    *(uint4*)((unsigned short*)x + (size_t)gid8 * 8) = v;
}

extern "C" void kernel_launch(void* const* d_in, const int* in_sizes, int n_in,
                              void* d_out, int out_size, void* d_ws, size_t ws_size,
                              hipStream_t stream) {
    const void* feat = d_in[0];
    const int* src = (const int*)d_in[1];
    const int* dst = (const int*)d_in[2];
    const void* w_fc0 = d_in[3];
    const void* al0 = d_in[4];
    const void* ar0 = d_in[5];
    const void* b0 = d_in[6];
    const void* w_lin0 = d_in[7];
    const void* g0 = d_in[8];
    const void* be0 = d_in[9];
    const void* w_fc1 = d_in[10];
    const void* al1 = d_in[11];
    const void* ar1 = d_in[12];
    const void* b1 = d_in[13];
    const void* w_lin1 = d_in[14];
    const void* g1 = d_in[15];
    const void* be1 = d_in[16];
    const void* w_fc2 = d_in[17];
    const void* al2 = d_in[18];
    const void* ar2 = d_in[19];
    const void* b2 = d_in[20];
    const void* w_lin2 = d_in[21];
    const void* bias_last = d_in[22];

    // ---- workspace guard: total need ~34.6 MB ----
    if (ws_size < 35000000) {
        sentinel_kernel<<<(out_size + 255) / 256, 256, 0, stream>>>((unsigned short*)d_out,
                                                                    out_size);
        return;
    }

    char* p = (char*)d_ws;
    auto alloc = [&](size_t bytes) {
        char* r = p;
        p += (bytes + 255) & ~(size_t)255;
        return r;
    };
    bf16* ftb = (bf16*)alloc((size_t)GN * 160 * 2);   // 16.0 MB
    bf16* hbuf = (bf16*)alloc((size_t)GN * 128 * 2);  // 12.8 MB
    float* elb = (float*)alloc((size_t)GN * 4 * 4);   // 0.8 MB
    float* erb = (float*)alloc((size_t)GN * 4 * 4);   // 0.8 MB
    int* indptr = (int*)alloc((size_t)(GN + 1) * 4);
    int* cursor = (int*)alloc((size_t)GN * 4);
    int* bsum = (int*)alloc(256 * 4);                 // block sums for 3-pass scan
    unsigned short* wmt = (unsigned short*)alloc(48 * 128 * 2);   // 12.3 KB
    unsigned short* wtf0 = (unsigned short*)alloc(128 * 128 * 2); // pre-transposed weights
    unsigned short* wtl0 = (unsigned short*)alloc(128 * 128 * 2);
    unsigned short* wtf1 = (unsigned short*)alloc(128 * 128 * 2);
    unsigned short* wtl1 = (unsigned short*)alloc(128 * 128 * 2);
    unsigned short* wtf2 = (unsigned short*)alloc(160 * 128 * 2);
    char* zbase = p;  // ---- zero-initialized region ----
    int* deg = (int*)alloc((size_t)GN * 4);
    int* csr = (int*)alloc((size_t)GE * 4);  // 3.2 MB
    float* gs0 = (float*)alloc(128 * 4);
    float* gq0 = (float*)alloc(128 * 4);
    float* gs1 = (float*)alloc(128 * 4);
    float* gq1 = (float*)alloc(128 * 4);
    int* flag = (int*)alloc(4);
    hipMemsetAsync(zbase, 0, (size_t)(p - zbase), stream);

    detect_kernel<<<1, 256, 0, stream>>>((const unsigned short*)feat, flag);

    // CSR build + weight precompute (independent, early)
    const int NB = (GN + 255) / 256;  // 196 scan blocks
    count_kernel<<<(GE + 255) / 256, 256, 0, stream>>>(dst, deg, GE);
    scan1_kernel<<<NB, 256, 0, stream>>>(deg, cursor, bsum, GN);   // cursor = per-block incl scan
    scan2_kernel<<<1, 256, 0, stream>>>(bsum, NB);                 // bsum = exclusive block offs
    scan3_kernel<<<NB, 256, 0, stream>>>(deg, cursor, bsum, indptr, cursor, GN);
    scatter_kernel<<<(GE + 255) / 256, 256, 0, stream>>>(src, dst, cursor, csr, GE);
    wmean_kernel<<<24, 256, 0, stream>>>(w_lin2, wmt, flag);
    wtrans_kernel<<<64, 256, 0, stream>>>(w_fc0, wtf0, 128, flag);
    wtrans_kernel<<<64, 256, 0, stream>>>(w_lin0, wtl0, 128, flag);
    wtrans_kernel<<<64, 256, 0, stream>>>(w_fc1, wtf1, 128, flag);
    wtrans_kernel<<<64, 256, 0, stream>>>(w_lin1, wtl1, 128, flag);
    wtrans_kernel<<<80, 256, 0, stream>>>(w_fc2, wtf2, 160, flag);

    dim3 g3(782, 3);
    const int AGGB = (GN + 3) / 4;  // 12500 blocks, 4 waves (nodes) each

    // ----- Layer 0 (fused: ftb = feat@w_fc0, hbuf = feat@w_lin0; feat read once) -----
    gemm_dual<<<782, 256, 0, stream>>>(feat, 1, wtf0, wtl0, ftb, hbuf, GN, flag);
    elr_kernel<<<(GN * 4 + 255) / 256, 256, 0, stream>>>(ftb, al0, ar0, elb, erb, GN, 32, flag);
    agg_wave<128, false><<<AGGB, 256, 0, stream>>>(ftb, elb, erb, indptr, csr, b0, nullptr,
                                                   hbuf, hbuf, nullptr, nullptr, flag);
    bn_stats<<<256, 128, 0, stream>>>(hbuf, gs0, gq0, GN);
    bn_apply<<<(GN * 16 + 255) / 256, 256, 0, stream>>>(hbuf, gs0, gq0, g0, be0, GN, flag);

    // ----- Layer 1 (fused: ftb = h1@w_fc1, hbuf <- h1@w_lin1 in-place) -----
    gemm_dual<<<782, 256, 0, stream>>>(hbuf, 0, wtf1, wtl1, ftb, hbuf, GN, flag);
    elr_kernel<<<(GN * 4 + 255) / 256, 256, 0, stream>>>(ftb, al1, ar1, elb, erb, GN, 32, flag);
    agg_wave<128, false><<<AGGB, 256, 0, stream>>>(ftb, elb, erb, indptr, csr, b1, nullptr,
                                                   hbuf, hbuf, nullptr, nullptr, flag);
    bn_stats<<<256, 128, 0, stream>>>(hbuf, gs1, gq1, GN);
    bn_apply<<<(GN * 16 + 255) / 256, 256, 0, stream>>>(hbuf, gs1, gq1, g1, be1, GN, flag);

    // ----- Layer 2 (final) -----
    gemm_tile<<<g3, 256, 0, stream>>>(hbuf, wtf2, ftb, GN, 160);
    elr_kernel<<<(GN * 4 + 255) / 256, 256, 0, stream>>>(ftb, al2, ar2, elb, erb, GN, 40, flag);
    skipmean_inplace<<<782, 256, 0, stream>>>(hbuf, wmt, GN);  // hbuf[:,0:40] <- h2 @ wmean
    agg_wave<160, true><<<AGGB, 256, 0, stream>>>(ftb, elb, erb, indptr, csr, b2, hbuf,
                                                  nullptr, nullptr, bias_last, d_out, flag);
}

// Round 5
// 459.776 us; speedup vs baseline: 1.9688x; 1.2885x over previous
//
#include <hip/hip_runtime.h>
#include <hip/hip_bf16.h>

#define GN 50000
#define GE 800000
#define GH 4
#define GFH 32
#define GC 40
#define GIN 128

typedef __hip_bfloat16 bf16;
typedef __attribute__((ext_vector_type(8))) short bf16x8;
typedef __attribute__((ext_vector_type(4))) float f32x4;

// mode m: 0 = tensor stored as bf16, 1 = stored as fp32
static __device__ __forceinline__ float ldx(const void* p, size_t i, int m) {
    if (m) return ((const float*)p)[i];
    return __bfloat162float(((const bf16*)p)[i]);
}
static __device__ __forceinline__ void stx(void* p, size_t i, int m, float v) {
    if (m) ((float*)p)[i] = v;
    else ((bf16*)p)[i] = __float2bfloat16(v);
}
static __device__ __forceinline__ unsigned short f2bfu(float v) {
    union { bf16 b; unsigned short u; } cv;
    cv.b = __float2bfloat16(v);
    return cv.u;
}
static __device__ __forceinline__ float lo16(unsigned u) { return __uint_as_float(u << 16); }
static __device__ __forceinline__ float hi16(unsigned u) { return __uint_as_float(u & 0xFFFF0000u); }
static __device__ __forceinline__ float guard_finite(float v) {
    if (!(v == v) || fabsf(v) > 1e30f) return 0.f;
    return v;
}

// ---------------- dtype probe: fp32 misread as bf16 shows wild exponents ----------------
__global__ void detect_kernel(const unsigned short* __restrict__ f, int* __restrict__ flag) {
    int t = threadIdx.x;  // 256
    unsigned short u = f[t];
    int e = (u >> 7) & 0xFF;
    if (e >= 0x8E) atomicAdd(flag, 1);  // |val| >= 2^15 or inf/nan -> not sane bf16 data
}

__global__ void sentinel_kernel(unsigned short* __restrict__ o, int n) {
    int i = blockIdx.x * blockDim.x + threadIdx.x;
    if (i < n) o[i] = 0x3F80;  // bf16 1.0
}

// ---------------- CSR build ----------------
__global__ void count_kernel(const int* __restrict__ dst, int* __restrict__ deg, int n) {
    int e = blockIdx.x * blockDim.x + threadIdx.x;
    if (e < n) {
        int d = dst[e];
        if (d >= 0 && d < GN) atomicAdd(&deg[d], 1);
    }
}

// ---- 3-pass device-wide scan ----
__global__ void scan1_kernel(const int* __restrict__ deg, int* __restrict__ tmp,
                             int* __restrict__ bsum, int n) {
    int tid = threadIdx.x;
    int i = blockIdx.x * 256 + tid;
    int v = (i < n) ? deg[i] : 0;
    int lane = tid & 63, wid = tid >> 6;
    int s = v;
#pragma unroll
    for (int off = 1; off < 64; off <<= 1) {
        int u = __shfl_up(s, off);
        if (lane >= off) s += u;
    }
    __shared__ int wsum[4];
    if (lane == 63) wsum[wid] = s;
    __syncthreads();
    int woff = 0;
#pragma unroll
    for (int w = 0; w < 4; w++) woff += (w < wid) ? wsum[w] : 0;
    int incl = s + woff;
    if (i < n) tmp[i] = incl;
    if (tid == 255) bsum[blockIdx.x] = incl;  // block total (zeros padded past n)
}

__global__ void scan2_kernel(int* __restrict__ bsum, int nb) {
    int tid = threadIdx.x;
    int v = (tid < nb) ? bsum[tid] : 0;
    int lane = tid & 63, wid = tid >> 6;
    int s = v;
#pragma unroll
    for (int off = 1; off < 64; off <<= 1) {
        int u = __shfl_up(s, off);
        if (lane >= off) s += u;
    }
    __shared__ int wsum[4];
    if (lane == 63) wsum[wid] = s;
    __syncthreads();
    int woff = 0;
#pragma unroll
    for (int w = 0; w < 4; w++) woff += (w < wid) ? wsum[w] : 0;
    if (tid < nb) bsum[tid] = s + woff - v;  // exclusive
}

__global__ void scan3_kernel(const int* __restrict__ deg, const int* __restrict__ tmp,
                             const int* __restrict__ bsum, int* __restrict__ indptr,
                             int* __restrict__ cursor, int n) {
    int i = blockIdx.x * 256 + threadIdx.x;
    if (i < n) {
        int incl = tmp[i] + bsum[blockIdx.x];
        indptr[i + 1] = incl;
        cursor[i] = incl - deg[i];
        if (i == 0) indptr[0] = 0;
    }
}

__global__ void scatter_kernel(const int* __restrict__ src, const int* __restrict__ dst,
                               int* __restrict__ cursor, int* __restrict__ csr_src, int n) {
    int e = blockIdx.x * blockDim.x + threadIdx.x;
    if (e < n) {
        int d = dst[e];
        if (d < 0 || d >= GN) return;
        int p = atomicAdd(&cursor[d], 1);
        if (p >= 0 && p < GE) csr_src[p] = src[e];
    }
}

// ---------------- w-mean: wmt[c][128] (c<48, zero-pad c>=40) = mean_h w_lin2[k][h*40+c] ----------------
__global__ void wmean_kernel(const void* __restrict__ w, unsigned short* __restrict__ wmt,
                             const int* __restrict__ flag) {
    int m = (*flag != 0) ? 1 : 0;
    int idx = blockIdx.x * blockDim.x + threadIdx.x;
    if (idx < 48 * 128) {
        int c = idx >> 7, k = idx & 127;
        float s = 0.f;
        if (c < 40) {
            s = 0.25f * (ldx(w, (size_t)k * 160 + c, m) + ldx(w, (size_t)k * 160 + 40 + c, m) +
                         ldx(w, (size_t)k * 160 + 80 + c, m) + ldx(w, (size_t)k * 160 + 120 + c, m));
        }
        wmt[c * 128 + k] = f2bfu(s);
    }
}

// ---------------- all weight transposes in ONE dispatch ----------------
// WT[c][128] = bf16(W[k][c]); 4x 128-col weights + 1x 160-col weight
__global__ void wtrans_all(const void* __restrict__ wf0, const void* __restrict__ wl0,
                           const void* __restrict__ wf1, const void* __restrict__ wl1,
                           const void* __restrict__ wf2, unsigned short* __restrict__ tf0,
                           unsigned short* __restrict__ tl0, unsigned short* __restrict__ tf1,
                           unsigned short* __restrict__ tl1, unsigned short* __restrict__ tf2,
                           const int* __restrict__ flag) {
    int m = (*flag != 0) ? 1 : 0;
    int idx = blockIdx.x * blockDim.x + threadIdx.x;
    if (idx < 4 * 16384) {
        int which = idx >> 14, local = idx & 16383;
        const void* w = (which == 0) ? wf0 : (which == 1) ? wl0 : (which == 2) ? wf1 : wl1;
        unsigned short* t = (which == 0) ? tf0 : (which == 1) ? tl0 : (which == 2) ? tf1 : tl1;
        int c = local & 127, k = local >> 7;
        t[(size_t)c * 128 + k] = f2bfu(ldx(w, (size_t)k * 128 + c, m));
    } else if (idx < 4 * 16384 + 160 * 128) {
        int local = idx - 4 * 16384;
        int c = local % 160, k = local / 160;
        tf2[(size_t)c * 128 + k] = f2bfu(ldx(wf2, (size_t)k * 160 + c, m));
    }
}

// ---------------- BN coefficients: y = relu(x*ka[c] + kb[c]) ----------------
__global__ void bn_coef(const float* __restrict__ gsum, const float* __restrict__ gsq,
                        const void* __restrict__ g, const void* __restrict__ be,
                        float* __restrict__ ka, float* __restrict__ kb, int n,
                        const int* __restrict__ flag) {
    int c = threadIdx.x;  // 128
    int m = (*flag != 0) ? 1 : 0;
    float inv_n = 1.f / (float)n;
    float mu = gsum[c] * inv_n;
    float var = gsq[c] * inv_n - mu * mu;
    float k = rsqrtf(fmaxf(var, 0.f) + 1e-5f) * ldx(g, c, m);
    ka[c] = k;
    kb[c] = ldx(be, c, m) - mu * k;
}

// BN+ReLU transform of a uint4 (8 bf16 cols starting at k0)
static __device__ __forceinline__ uint4 bnx8(uint4 v, int k0, const float* __restrict__ ka,
                                             const float* __restrict__ kb) {
    unsigned* pw = (unsigned*)&v;
#pragma unroll
    for (int j = 0; j < 4; j++) {
        int c = k0 + 2 * j;
        float y0 = fmaf(lo16(pw[j]), ka[c], kb[c]);
        float y1 = fmaf(hi16(pw[j]), ka[c + 1], kb[c + 1]);
        y0 = y0 > 0.f ? y0 : 0.f;
        y1 = y1 > 0.f ? y1 : 0.f;
        pw[j] = (unsigned)f2bfu(y0) | ((unsigned)f2bfu(y1) << 16);
    }
    return v;
}

// ---------------- MFMA dual GEMM: Y1 = X@WT1^T, Y2 = X@WT2^T (both 128 cols); X staged once ----
// Optional fused BN+ReLU on X staging (ka != nullptr). Y2 may alias X (row-exclusive blocks).
__global__ __launch_bounds__(256) void gemm_dual(const void* __restrict__ X, int xext,
                                                 const unsigned short* __restrict__ WT1,
                                                 const unsigned short* __restrict__ WT2,
                                                 bf16* __restrict__ Y1, bf16* __restrict__ Y2,
                                                 int nrows, const float* __restrict__ ka,
                                                 const float* __restrict__ kb,
                                                 const int* __restrict__ flag) {
    constexpr int LDX = 136;
    __shared__ unsigned short Xs[64 * LDX];   // [r][k]
    __shared__ unsigned short Wt[128 * LDX];  // [c][k], reused for W1 then W2
    int xfp32 = xext && (*flag != 0);
    int tid = threadIdx.x;
    int rb = blockIdx.x * 64;

    if (xfp32) {
#pragma unroll
        for (int it = 0; it < 8; it++) {  // float4 = 4 elems
            int e = (tid + it * 256) * 4;
            int r = e >> 7, k0 = e & 127;
            int row = rb + r;
            float4 v = {0.f, 0.f, 0.f, 0.f};
            if (row < nrows) v = *(const float4*)((const float*)X + (size_t)row * 128 + k0);
            unsigned lo = (unsigned)f2bfu(v.x) | ((unsigned)f2bfu(v.y) << 16);
            unsigned hi = (unsigned)f2bfu(v.z) | ((unsigned)f2bfu(v.w) << 16);
            uint2 o = {lo, hi};
            *(uint2*)&Xs[r * LDX + k0] = o;
        }
    } else {
#pragma unroll
        for (int it = 0; it < 4; it++) {  // uint4 = 8 bf16
            int e = (tid + it * 256) * 8;
            int r = e >> 7, k0 = e & 127;
            int row = rb + r;
            uint4 v = {0u, 0u, 0u, 0u};
            if (row < nrows) v = *(const uint4*)((const unsigned short*)X + (size_t)row * 128 + k0);
            if (ka) v = bnx8(v, k0, ka, kb);
            *(uint4*)&Xs[r * LDX + k0] = v;
        }
    }
#pragma unroll
    for (int it = 0; it < 8; it++) {  // 128x128 weight tile
        int e = (tid + it * 256) * 8;
        int c = e >> 7, k0 = e & 127;
        *(uint4*)&Wt[c * LDX + k0] = *(const uint4*)(WT1 + (size_t)c * 128 + k0);
    }
    __syncthreads();

    int wave = tid >> 6, lane = tid & 63;
    int lr = lane & 15, quad = lane >> 4;
    int mrow = wave * 16 + lr;
    int drow = rb + wave * 16 + quad * 4;

    {
        f32x4 acc[8] = {};
        for (int kk = 0; kk < 128; kk += 32) {
            bf16x8 a = *(const bf16x8*)&Xs[mrow * LDX + kk + quad * 8];
#pragma unroll
            for (int nt = 0; nt < 8; nt++) {
                bf16x8 b = *(const bf16x8*)&Wt[(nt * 16 + lr) * LDX + kk + quad * 8];
                acc[nt] = __builtin_amdgcn_mfma_f32_16x16x32_bf16(a, b, acc[nt], 0, 0, 0);
            }
        }
#pragma unroll
        for (int nt = 0; nt < 8; nt++) {
            int col = nt * 16 + lr;
#pragma unroll
            for (int i = 0; i < 4; i++) {
                int row = drow + i;
                if (row < nrows) Y1[(size_t)row * 128 + col] = __float2bfloat16(acc[nt][i]);
            }
        }
    }
    __syncthreads();  // all waves done reading W1 tile
#pragma unroll
    for (int it = 0; it < 8; it++) {
        int e = (tid + it * 256) * 8;
        int c = e >> 7, k0 = e & 127;
        *(uint4*)&Wt[c * LDX + k0] = *(const uint4*)(WT2 + (size_t)c * 128 + k0);
    }
    __syncthreads();
    {
        f32x4 acc[8] = {};
        for (int kk = 0; kk < 128; kk += 32) {
            bf16x8 a = *(const bf16x8*)&Xs[mrow * LDX + kk + quad * 8];
#pragma unroll
            for (int nt = 0; nt < 8; nt++) {
                bf16x8 b = *(const bf16x8*)&Wt[(nt * 16 + lr) * LDX + kk + quad * 8];
                acc[nt] = __builtin_amdgcn_mfma_f32_16x16x32_bf16(a, b, acc[nt], 0, 0, 0);
            }
        }
#pragma unroll
        for (int nt = 0; nt < 8; nt++) {
            int col = nt * 16 + lr;
#pragma unroll
            for (int i = 0; i < 4; i++) {
                int row = drow + i;
                if (row < nrows) Y2[(size_t)row * 128 + col] = __float2bfloat16(acc[nt][i]);
            }
        }
    }
}

// ---------------- layer-2 fused GEMM: stage BN(hbuf) once ----------------
// WT2b: [208][128]  rows 0..159 = w_fc2^T, rows 160..207 = wmt (zero-pad >=40)
// writes: Y[.,0:160] = X@w_fc2 ; X[.,0:40] = X@wmt^T (in-place, row-exclusive)
__global__ __launch_bounds__(256) void gemm_final(bf16* __restrict__ X,
                                                  const unsigned short* __restrict__ WT,
                                                  bf16* __restrict__ Y, int nrows,
                                                  const float* __restrict__ ka,
                                                  const float* __restrict__ kb) {
    constexpr int LDX = 136;
    __shared__ unsigned short Xs[64 * LDX];   // [r][k]
    __shared__ unsigned short Wt[128 * LDX];  // phase1: rows 0..127; phase2: rows 128..207
    int tid = threadIdx.x;
    int rb = blockIdx.x * 64;

#pragma unroll
    for (int it = 0; it < 4; it++) {
        int e = (tid + it * 256) * 8;
        int r = e >> 7, k0 = e & 127;
        int row = rb + r;
        uint4 v = {0u, 0u, 0u, 0u};
        if (row < nrows) v = *(const uint4*)((const unsigned short*)X + (size_t)row * 128 + k0);
        v = bnx8(v, k0, ka, kb);
        *(uint4*)&Xs[r * LDX + k0] = v;
    }
#pragma unroll
    for (int it = 0; it < 8; it++) {
        int e = (tid + it * 256) * 8;
        int c = e >> 7, k0 = e & 127;
        *(uint4*)&Wt[c * LDX + k0] = *(const uint4*)(WT + (size_t)c * 128 + k0);
    }
    __syncthreads();

    int wave = tid >> 6, lane = tid & 63;
    int lr = lane & 15, quad = lane >> 4;
    int mrow = wave * 16 + lr;
    int drow = rb + wave * 16 + quad * 4;

    {  // phase 1: output cols 0..127
        f32x4 acc[8] = {};
        for (int kk = 0; kk < 128; kk += 32) {
            bf16x8 a = *(const bf16x8*)&Xs[mrow * LDX + kk + quad * 8];
#pragma unroll
            for (int nt = 0; nt < 8; nt++) {
                bf16x8 b = *(const bf16x8*)&Wt[(nt * 16 + lr) * LDX + kk + quad * 8];
                acc[nt] = __builtin_amdgcn_mfma_f32_16x16x32_bf16(a, b, acc[nt], 0, 0, 0);
            }
        }
#pragma unroll
        for (int nt = 0; nt < 8; nt++) {
            int col = nt * 16 + lr;
#pragma unroll
            for (int i = 0; i < 4; i++) {
                int row = drow + i;
                if (row < nrows) Y[(size_t)row * 160 + col] = __float2bfloat16(acc[nt][i]);
            }
        }
    }
    __syncthreads();
#pragma unroll
    for (int it = 0; it < 5; it++) {  // 80 rows (128..207)
        int e = (tid + it * 256) * 8;
        int c = e >> 7, k0 = e & 127;
        *(uint4*)&Wt[c * LDX + k0] = *(const uint4*)(WT + (size_t)(128 + c) * 128 + k0);
    }
    __syncthreads();
    {  // phase 2: output cols 128..159 (->Y) and skipmean cols 0..39 (->X)
        f32x4 acc[5] = {};
        for (int kk = 0; kk < 128; kk += 32) {
            bf16x8 a = *(const bf16x8*)&Xs[mrow * LDX + kk + quad * 8];
#pragma unroll
            for (int nt = 0; nt < 5; nt++) {
                bf16x8 b = *(const bf16x8*)&Wt[(nt * 16 + lr) * LDX + kk + quad * 8];
                acc[nt] = __builtin_amdgcn_mfma_f32_16x16x32_bf16(a, b, acc[nt], 0, 0, 0);
            }
        }
#pragma unroll
        for (int nt = 0; nt < 5; nt++) {
            int colg = 128 + nt * 16 + lr;
#pragma unroll
            for (int i = 0; i < 4; i++) {
                int row = drow + i;
                if (row >= nrows) continue;
                if (colg < 160) {
                    Y[(size_t)row * 160 + colg] = __float2bfloat16(acc[nt][i]);
                } else {
                    int sc = colg - 160;
                    if (sc < 40) X[(size_t)row * 128 + sc] = __float2bfloat16(acc[nt][i]);
                }
            }
        }
    }
}

// ---------------- el/er: [N,H] dot over F (vectorized bf16x8 loads) ----------------
__global__ void elr_kernel(const bf16* __restrict__ ft, const void* __restrict__ al,
                           const void* __restrict__ ar, float* __restrict__ el,
                           float* __restrict__ er, int n, int F, const int* __restrict__ flag) {
    int m = (*flag != 0) ? 1 : 0;
    int gid = blockIdx.x * blockDim.x + threadIdx.x;
    if (gid >= n * 4) return;
    int nid = gid >> 2, h = gid & 3;
    const bf16* f = ft + (size_t)nid * (4 * F) + h * F;
    float sl = 0.f, sr = 0.f;
    for (int i0 = 0; i0 < F; i0 += 8) {
        bf16x8 v8 = *(const bf16x8*)(f + i0);
#pragma unroll
        for (int i = 0; i < 8; i++) {
            float v = __uint_as_float(((unsigned)(unsigned short)v8[i]) << 16);
            sl += v * ldx(al, h * F + i0 + i, m);
            sr += v * ldx(ar, h * F + i0 + i, m);
        }
    }
    el[gid] = sl;
    er[gid] = sr;
}

// ---------------- per-dst softmax + aggregation: ONE WAVE PER NODE, zero barriers ----------------
// 16-deep gather batch per chunk: all 16 row-loads in flight before any consumption.
template <int FTOT, bool FINAL>
__global__ __launch_bounds__(256) void agg_wave(
    const bf16* __restrict__ ft, const float* __restrict__ el, const float* __restrict__ er,
    const int* __restrict__ indptr, const int* __restrict__ csr_src,
    const void* __restrict__ bias, const void* __restrict__ h_in,
    const bf16* __restrict__ skip_pre, bf16* __restrict__ out,
    const void* __restrict__ bias_last, void* __restrict__ fout,
    const int* __restrict__ flag) {
    constexpr int HF = FTOT / 4;
    int m = (*flag != 0) ? 1 : 0;
    int lane = threadIdx.x & 63;
    int v = blockIdx.x * 4 + (threadIdx.x >> 6);
    if (v >= GN) return;
    int beg = indptr[v], end = indptr[v + 1];
    beg = max(0, min(beg, GE));
    end = max(beg, min(end, GE));

    int h = lane & 3, jl = lane >> 2;  // weight-phase mapping: edge slot jl, head h
    int c0 = 2 * lane;                 // gather-phase feature pair
    int h0 = c0 / HF;
    float erv = er[v * 4 + h];

    float a0 = 0.f, a1 = 0.f, a2 = 0.f, a3 = 0.f;
    float s_part = 0.f;

    for (int cb = beg; cb < end; cb += 16) {
        int chn = end - cb;
        chn = chn < 16 ? chn : 16;
        // ---- weight phase (this chunk's 16 edges) ----
        int u = csr_src[cb + (jl < chn ? jl : chn - 1)];
        u = min(max(u, 0), GN - 1);
        float e = el[u * 4 + h] + erv;
        e = e > 0.f ? e : 0.2f * e;
        float w = (jl < chn) ? __expf(fminf(e, 60.f)) : 0.f;
        s_part += w;
        // ---- gather phase: 16 independent row loads issued together (w=0 pads OOB) ----
        unsigned pq[16];
        float wqv[16];
        unsigned pbq[16];
#pragma unroll
        for (int q = 0; q < 16; q++) {
            int j4 = q * 4;
            int us = __builtin_amdgcn_readlane(u, j4);  // SGPR base, no LDS-pipe dep
            pq[q] = *(const unsigned*)(ft + (size_t)us * FTOT + c0);
            wqv[q] = __shfl(w, j4 + h0);
            if constexpr (FINAL) {
                if (lane < 16) {
                    pbq[q] = *(const unsigned*)(ft + (size_t)us * FTOT + 128 + c0);
                }
            }
        }
#pragma unroll
        for (int q = 0; q < 16; q++) {
            a0 += wqv[q] * lo16(pq[q]);
            a1 += wqv[q] * hi16(pq[q]);
            if constexpr (FINAL) {
                // pair1 cols 128..159 are head 3: uniform weight via readlane
                float wb = __uint_as_float(
                    __builtin_amdgcn_readlane(__float_as_uint(w), q * 4 + 3));
                if (lane < 16) {
                    a2 += wb * lo16(pbq[q]);
                    a3 += wb * hi16(pbq[q]);
                }
            }
        }
    }

    // ---- s reduction: butterfly over slot bits (head preserved in lane&3) ----
#pragma unroll
    for (int off = 4; off < 64; off <<= 1) s_part += __shfl_xor(s_part, off);
    float s0 = __shfl(s_part, h0);  // lane h0 (0..3) holds head-h0 total

    float r0 = (s0 > 0.f) ? a0 / s0 : 0.f;
    float r1 = (s0 > 0.f) ? a1 / s0 : 0.f;

    if constexpr (!FINAL) {
        unsigned pk = *(const unsigned*)(skip_pre + (size_t)v * FTOT + c0);
        float o0 = r0 + ldx(bias, c0, m) + lo16(pk);
        float o1 = r1 + ldx(bias, c0 + 1, m) + hi16(pk);
        unsigned po = ((unsigned)f2bfu(guard_finite(o1)) << 16) |
                      (unsigned)f2bfu(guard_finite(o0));
        *(unsigned*)(out + (size_t)v * FTOT + c0) = po;
    } else {
        float s3 = __shfl(s_part, 3);
        float o0 = r0 + ldx(bias, c0, m);
        float o1 = r1 + ldx(bias, c0 + 1, m);
        float r2 = (s3 > 0.f) ? a2 / s3 : 0.f;
        float r3 = (s3 > 0.f) ? a3 / s3 : 0.f;
        int cb0 = 128 + c0;  // meaningful for lane<16 only
        float o2 = r2 + ldx(bias, (cb0 < FTOT) ? cb0 : 0, m);
        float o3 = r3 + ldx(bias, (cb0 + 1 < FTOT) ? cb0 + 1 : 1, m);

        // head-average: lane t<40 needs cols t, t+40, t+80, t+120 (all parity t&1)
        int t = lane;
        bool od = (t & 1);
        int sA = (t >> 1) & 63;
        int sB = ((t + 40) >> 1) & 63;
        int sC = ((t + 80) >> 1) & 63;
        int sD1 = ((t + 120) >> 1) & 63;          // valid when t<8 (col<128, from o0/o1)
        int sD2 = ((t >= 8 ? t - 8 : 0) >> 1);    // valid when t>=8 (col>=128, from o2/o3)
        float vA0 = __shfl(o0, sA), vA1 = __shfl(o1, sA);
        float vB0 = __shfl(o0, sB), vB1 = __shfl(o1, sB);
        float vC0 = __shfl(o0, sC), vC1 = __shfl(o1, sC);
        float vD10 = __shfl(o0, sD1), vD11 = __shfl(o1, sD1);
        float vD20 = __shfl(o2, sD2), vD21 = __shfl(o3, sD2);
        float vA = od ? vA1 : vA0;
        float vB = od ? vB1 : vB0;
        float vC = od ? vC1 : vC0;
        float vD = (t < 8) ? (od ? vD11 : vD10) : (od ? vD21 : vD20);

        float x = -3.0e38f;
        if (t < 40) {
            float sm = __bfloat162float(((const bf16*)h_in)[(size_t)v * 128 + t]);
            x = 0.25f * (vA + vB + vC + vD) + sm + ldx(bias_last, t, m);
        }
        float mx = x;
#pragma unroll
        for (int off = 1; off < 64; off <<= 1) mx = fmaxf(mx, __shfl_xor(mx, off));
        float ex = (t < 40) ? __expf(x - mx) : 0.f;
        float sum = ex;
#pragma unroll
        for (int off = 1; off < 64; off <<= 1) sum += __shfl_xor(sum, off);
        if (t < 40) stx(fout, (size_t)v * 40 + t, m, guard_finite(x - mx - __logf(sum)));
    }
}

// ---------------- BatchNorm stats on bf16 [N,128]: vectorized + LDS reduce ----------------
__global__ void bn_stats(const bf16* __restrict__ x, float* __restrict__ gsum,
                         float* __restrict__ gsq, int n) {
    __shared__ float ls[128], lq[128];
    int tid = threadIdx.x;  // 256
    if (tid < 128) {
        ls[tid] = 0.f;
        lq[tid] = 0.f;
    }
    __syncthreads();
    int rg = tid >> 4;         // 0..15 row substream
    int c8 = (tid & 15) * 8;   // col start
    int rows_per_block = (n + gridDim.x - 1) / gridDim.x;
    int r0 = blockIdx.x * rows_per_block;
    int r1 = min(n, r0 + rows_per_block);
    float s[8] = {}, q[8] = {};
    for (int r = r0 + rg; r < r1; r += 16) {
        uint4 v = *(const uint4*)((const unsigned short*)x + (size_t)r * 128 + c8);
        unsigned* pw = (unsigned*)&v;
#pragma unroll
        for (int i = 0; i < 4; i++) {
            float v0 = lo16(pw[i]), v1 = hi16(pw[i]);
            s[2 * i] += v0;
            q[2 * i] += v0 * v0;
            s[2 * i + 1] += v1;
            q[2 * i + 1] += v1 * v1;
        }
    }
#pragma unroll
    for (int i = 0; i < 8; i++) {
        atomicAdd(&ls[c8 + i], s[i]);
        atomicAdd(&lq[c8 + i], q[i]);
    }
    __syncthreads();
    if (tid < 128) {
        atomicAdd(&gsum[tid], ls[tid]);
        atomicAdd(&gsq[tid], lq[tid]);
    }
}

extern "C" void kernel_launch(void* const* d_in, const int* in_sizes, int n_in,
                              void* d_out, int out_size, void* d_ws, size_t ws_size,
                              hipStream_t stream) {
    const void* feat = d_in[0];
    const int* src = (const int*)d_in[1];
    const int* dst = (const int*)d_in[2];
    const void* w_fc0 = d_in[3];
    const void* al0 = d_in[4];
    const void* ar0 = d_in[5];
    const void* b0 = d_in[6];
    const void* w_lin0 = d_in[7];
    const void* g0 = d_in[8];
    const void* be0 = d_in[9];
    const void* w_fc1 = d_in[10];
    const void* al1 = d_in[11];
    const void* ar1 = d_in[12];
    const void* b1 = d_in[13];
    const void* w_lin1 = d_in[14];
    const void* g1 = d_in[15];
    const void* be1 = d_in[16];
    const void* w_fc2 = d_in[17];
    const void* al2 = d_in[18];
    const void* ar2 = d_in[19];
    const void* b2 = d_in[20];
    const void* w_lin2 = d_in[21];
    const void* bias_last = d_in[22];

    // ---- workspace guard: total need ~34.6 MB ----
    if (ws_size < 35000000) {
        sentinel_kernel<<<(out_size + 255) / 256, 256, 0, stream>>>((unsigned short*)d_out,
                                                                    out_size);
        return;
    }

    char* p = (char*)d_ws;
    auto alloc = [&](size_t bytes) {
        char* r = p;
        p += (bytes + 255) & ~(size_t)255;
        return r;
    };
    bf16* ftb = (bf16*)alloc((size_t)GN * 160 * 2);   // 16.0 MB
    bf16* hbuf = (bf16*)alloc((size_t)GN * 128 * 2);  // 12.8 MB
    float* elb = (float*)alloc((size_t)GN * 4 * 4);   // 0.8 MB
    float* erb = (float*)alloc((size_t)GN * 4 * 4);   // 0.8 MB
    int* indptr = (int*)alloc((size_t)(GN + 1) * 4);
    int* cursor = (int*)alloc((size_t)GN * 4);
    int* bsum = (int*)alloc(256 * 4);                 // block sums for 3-pass scan
    unsigned short* wtf0 = (unsigned short*)alloc(128 * 128 * 2);  // pre-transposed weights
    unsigned short* wtl0 = (unsigned short*)alloc(128 * 128 * 2);
    unsigned short* wtf1 = (unsigned short*)alloc(128 * 128 * 2);
    unsigned short* wtl1 = (unsigned short*)alloc(128 * 128 * 2);
    unsigned short* wtf2 = (unsigned short*)alloc(208 * 128 * 2);  // rows 160..207 = wmt
    float* ka0 = (float*)alloc(128 * 4);
    float* kb0 = (float*)alloc(128 * 4);
    float* ka1 = (float*)alloc(128 * 4);
    float* kb1 = (float*)alloc(128 * 4);
    char* zbase = p;  // ---- zero-initialized region ----
    int* deg = (int*)alloc((size_t)GN * 4);
    int* csr = (int*)alloc((size_t)GE * 4);  // 3.2 MB
    float* gs0 = (float*)alloc(128 * 4);
    float* gq0 = (float*)alloc(128 * 4);
    float* gs1 = (float*)alloc(128 * 4);
    float* gq1 = (float*)alloc(128 * 4);
    int* flag = (int*)alloc(4);
    hipMemsetAsync(zbase, 0, (size_t)(p - zbase), stream);

    unsigned short* wmt = wtf2 + 160 * 128;  // wmean rows appended to WT2

    detect_kernel<<<1, 256, 0, stream>>>((const unsigned short*)feat, flag);

    // CSR build + weight precompute (independent, early)
    const int NB = (GN + 255) / 256;  // 196 scan blocks
    count_kernel<<<(GE + 255) / 256, 256, 0, stream>>>(dst, deg, GE);
    scan1_kernel<<<NB, 256, 0, stream>>>(deg, cursor, bsum, GN);   // cursor = per-block incl scan
    scan2_kernel<<<1, 256, 0, stream>>>(bsum, NB);                 // bsum = exclusive block offs
    scan3_kernel<<<NB, 256, 0, stream>>>(deg, cursor, bsum, indptr, cursor, GN);
    scatter_kernel<<<(GE + 255) / 256, 256, 0, stream>>>(src, dst, cursor, csr, GE);
    wmean_kernel<<<24, 256, 0, stream>>>(w_lin2, wmt, flag);
    wtrans_all<<<(4 * 16384 + 160 * 128 + 255) / 256, 256, 0, stream>>>(
        w_fc0, w_lin0, w_fc1, w_lin1, w_fc2, wtf0, wtl0, wtf1, wtl1, wtf2, flag);

    const int AGGB = (GN + 3) / 4;  // 12500 blocks, 4 waves (nodes) each

    // ----- Layer 0 (fused: ftb = feat@w_fc0, hbuf = feat@w_lin0; feat read once) -----
    gemm_dual<<<782, 256, 0, stream>>>(feat, 1, wtf0, wtl0, ftb, hbuf, GN, nullptr, nullptr,
                                       flag);
    elr_kernel<<<(GN * 4 + 255) / 256, 256, 0, stream>>>(ftb, al0, ar0, elb, erb, GN, 32, flag);
    agg_wave<128, false><<<AGGB, 256, 0, stream>>>(ftb, elb, erb, indptr, csr, b0, nullptr,
                                                   hbuf, hbuf, nullptr, nullptr, flag);
    bn_stats<<<256, 256, 0, stream>>>(hbuf, gs0, gq0, GN);
    bn_coef<<<1, 128, 0, stream>>>(gs0, gq0, g0, be0, ka0, kb0, GN, flag);

    // ----- Layer 1 (fused: BN0+ReLU on staging; ftb = h1@w_fc1, hbuf <- h1@w_lin1) -----
    gemm_dual<<<782, 256, 0, stream>>>(hbuf, 0, wtf1, wtl1, ftb, hbuf, GN, ka0, kb0, flag);
    elr_kernel<<<(GN * 4 + 255) / 256, 256, 0, stream>>>(ftb, al1, ar1, elb, erb, GN, 32, flag);
    agg_wave<128, false><<<AGGB, 256, 0, stream>>>(ftb, elb, erb, indptr, csr, b1, nullptr,
                                                   hbuf, hbuf, nullptr, nullptr, flag);
    bn_stats<<<256, 256, 0, stream>>>(hbuf, gs1, gq1, GN);
    bn_coef<<<1, 128, 0, stream>>>(gs1, gq1, g1, be1, ka1, kb1, GN, flag);

    // ----- Layer 2 (fused: BN1+ReLU staging; ftb = h2@w_fc2 [160 cols]; hbuf[:,0:40] = skipmean) -----
    gemm_final<<<782, 256, 0, stream>>>(hbuf, wtf2, ftb, GN, ka1, kb1);
    elr_kernel<<<(GN * 4 + 255) / 256, 256, 0, stream>>>(ftb, al2, ar2, elb, erb, GN, 40, flag);
    agg_wave<160, true><<<AGGB, 256, 0, stream>>>(ftb, elb, erb, indptr, csr, b2, hbuf,
                                                  nullptr, nullptr, bias_last, d_out, flag);
}

// Round 6
// 440.641 us; speedup vs baseline: 2.0543x; 1.0434x over previous
//
#include <hip/hip_runtime.h>
#include <hip/hip_bf16.h>

#define GN 50000
#define GE 800000
#define GH 4
#define GFH 32
#define GC 40
#define GIN 128

typedef __hip_bfloat16 bf16;
typedef __attribute__((ext_vector_type(8))) short bf16x8;
typedef __attribute__((ext_vector_type(4))) float f32x4;

// mode m: 0 = tensor stored as bf16, 1 = stored as fp32
static __device__ __forceinline__ float ldx(const void* p, size_t i, int m) {
    if (m) return ((const float*)p)[i];
    return __bfloat162float(((const bf16*)p)[i]);
}
static __device__ __forceinline__ void stx(void* p, size_t i, int m, float v) {
    if (m) ((float*)p)[i] = v;
    else ((bf16*)p)[i] = __float2bfloat16(v);
}
static __device__ __forceinline__ unsigned short f2bfu(float v) {
    union { bf16 b; unsigned short u; } cv;
    cv.b = __float2bfloat16(v);
    return cv.u;
}
static __device__ __forceinline__ float lo16(unsigned u) { return __uint_as_float(u << 16); }
static __device__ __forceinline__ float hi16(unsigned u) { return __uint_as_float(u & 0xFFFF0000u); }
static __device__ __forceinline__ float guard_finite(float v) {
    if (!(v == v) || fabsf(v) > 1e30f) return 0.f;
    return v;
}

// ---------------- dtype probe: fp32 misread as bf16 shows wild exponents ----------------
__global__ void detect_kernel(const unsigned short* __restrict__ f, int* __restrict__ flag) {
    int t = threadIdx.x;  // 256
    unsigned short u = f[t];
    int e = (u >> 7) & 0xFF;
    if (e >= 0x8E) atomicAdd(flag, 1);  // |val| >= 2^15 or inf/nan -> not sane bf16 data
}

__global__ void sentinel_kernel(unsigned short* __restrict__ o, int n) {
    int i = blockIdx.x * blockDim.x + threadIdx.x;
    if (i < n) o[i] = 0x3F80;  // bf16 1.0
}

// ---------------- CSR build ----------------
__global__ void count_kernel(const int* __restrict__ dst, int* __restrict__ deg, int n) {
    int e = blockIdx.x * blockDim.x + threadIdx.x;
    if (e < n) {
        int d = dst[e];
        if (d >= 0 && d < GN) atomicAdd(&deg[d], 1);
    }
}

// ---- 3-pass device-wide scan ----
__global__ void scan1_kernel(const int* __restrict__ deg, int* __restrict__ tmp,
                             int* __restrict__ bsum, int n) {
    int tid = threadIdx.x;
    int i = blockIdx.x * 256 + tid;
    int v = (i < n) ? deg[i] : 0;
    int lane = tid & 63, wid = tid >> 6;
    int s = v;
#pragma unroll
    for (int off = 1; off < 64; off <<= 1) {
        int u = __shfl_up(s, off);
        if (lane >= off) s += u;
    }
    __shared__ int wsum[4];
    if (lane == 63) wsum[wid] = s;
    __syncthreads();
    int woff = 0;
#pragma unroll
    for (int w = 0; w < 4; w++) woff += (w < wid) ? wsum[w] : 0;
    int incl = s + woff;
    if (i < n) tmp[i] = incl;
    if (tid == 255) bsum[blockIdx.x] = incl;  // block total (zeros padded past n)
}

__global__ void scan2_kernel(int* __restrict__ bsum, int nb) {
    int tid = threadIdx.x;
    int v = (tid < nb) ? bsum[tid] : 0;
    int lane = tid & 63, wid = tid >> 6;
    int s = v;
#pragma unroll
    for (int off = 1; off < 64; off <<= 1) {
        int u = __shfl_up(s, off);
        if (lane >= off) s += u;
    }
    __shared__ int wsum[4];
    if (lane == 63) wsum[wid] = s;
    __syncthreads();
    int woff = 0;
#pragma unroll
    for (int w = 0; w < 4; w++) woff += (w < wid) ? wsum[w] : 0;
    if (tid < nb) bsum[tid] = s + woff - v;  // exclusive
}

__global__ void scan3_kernel(const int* __restrict__ deg, const int* __restrict__ tmp,
                             const int* __restrict__ bsum, int* __restrict__ indptr,
                             int* __restrict__ cursor, int n) {
    int i = blockIdx.x * 256 + threadIdx.x;
    if (i < n) {
        int incl = tmp[i] + bsum[blockIdx.x];
        indptr[i + 1] = incl;
        cursor[i] = incl - deg[i];
        if (i == 0) indptr[0] = 0;
    }
}

__global__ void scatter_kernel(const int* __restrict__ src, const int* __restrict__ dst,
                               int* __restrict__ cursor, int* __restrict__ csr_src, int n) {
    int e = blockIdx.x * blockDim.x + threadIdx.x;
    if (e < n) {
        int d = dst[e];
        if (d < 0 || d >= GN) return;
        int p = atomicAdd(&cursor[d], 1);
        if (p >= 0 && p < GE) csr_src[p] = src[e];
    }
}

// ---------------- w-mean: wmt[c][128] (c<48, zero-pad c>=40) = mean_h w_lin2[k][h*40+c] ----------------
__global__ void wmean_kernel(const void* __restrict__ w, unsigned short* __restrict__ wmt,
                             const int* __restrict__ flag) {
    int m = (*flag != 0) ? 1 : 0;
    int idx = blockIdx.x * blockDim.x + threadIdx.x;
    if (idx < 48 * 128) {
        int c = idx >> 7, k = idx & 127;
        float s = 0.f;
        if (c < 40) {
            s = 0.25f * (ldx(w, (size_t)k * 160 + c, m) + ldx(w, (size_t)k * 160 + 40 + c, m) +
                         ldx(w, (size_t)k * 160 + 80 + c, m) + ldx(w, (size_t)k * 160 + 120 + c, m));
        }
        wmt[c * 128 + k] = f2bfu(s);
    }
}

// ---------------- all weight transposes in ONE dispatch ----------------
__global__ void wtrans_all(const void* __restrict__ wf0, const void* __restrict__ wl0,
                           const void* __restrict__ wf1, const void* __restrict__ wl1,
                           const void* __restrict__ wf2, unsigned short* __restrict__ tf0,
                           unsigned short* __restrict__ tl0, unsigned short* __restrict__ tf1,
                           unsigned short* __restrict__ tl1, unsigned short* __restrict__ tf2,
                           const int* __restrict__ flag) {
    int m = (*flag != 0) ? 1 : 0;
    int idx = blockIdx.x * blockDim.x + threadIdx.x;
    if (idx < 4 * 16384) {
        int which = idx >> 14, local = idx & 16383;
        const void* w = (which == 0) ? wf0 : (which == 1) ? wl0 : (which == 2) ? wf1 : wl1;
        unsigned short* t = (which == 0) ? tf0 : (which == 1) ? tl0 : (which == 2) ? tf1 : tl1;
        int c = local & 127, k = local >> 7;
        t[(size_t)c * 128 + k] = f2bfu(ldx(w, (size_t)k * 128 + c, m));
    } else if (idx < 4 * 16384 + 160 * 128) {
        int local = idx - 4 * 16384;
        int c = local % 160, k = local / 160;
        tf2[(size_t)c * 128 + k] = f2bfu(ldx(wf2, (size_t)k * 160 + c, m));
    }
}

// ---------------- BN coefficients: y = relu(x*ka[c] + kb[c]) ----------------
__global__ void bn_coef(const float* __restrict__ gsum, const float* __restrict__ gsq,
                        const void* __restrict__ g, const void* __restrict__ be,
                        float* __restrict__ ka, float* __restrict__ kb, int n,
                        const int* __restrict__ flag) {
    int c = threadIdx.x;  // 128
    int m = (*flag != 0) ? 1 : 0;
    float inv_n = 1.f / (float)n;
    float mu = gsum[c] * inv_n;
    float var = gsq[c] * inv_n - mu * mu;
    float k = rsqrtf(fmaxf(var, 0.f) + 1e-5f) * ldx(g, c, m);
    ka[c] = k;
    kb[c] = ldx(be, c, m) - mu * k;
}

// BN+ReLU transform of a uint4 (8 bf16 cols starting at k0)
static __device__ __forceinline__ uint4 bnx8(uint4 v, int k0, const float* __restrict__ ka,
                                             const float* __restrict__ kb) {
    unsigned* pw = (unsigned*)&v;
#pragma unroll
    for (int j = 0; j < 4; j++) {
        int c = k0 + 2 * j;
        float y0 = fmaf(lo16(pw[j]), ka[c], kb[c]);
        float y1 = fmaf(hi16(pw[j]), ka[c + 1], kb[c + 1]);
        y0 = y0 > 0.f ? y0 : 0.f;
        y1 = y1 > 0.f ? y1 : 0.f;
        pw[j] = (unsigned)f2bfu(y0) | ((unsigned)f2bfu(y1) << 16);
    }
    return v;
}

// ---------------- MFMA dual GEMM + fused el/er epilogue ----------------
// Y1 = X@WT1^T (=ft), Y2 = X@WT2^T; X staged once. Optional BN+ReLU on X staging.
// el/er computed from phase-1 acc (fp32 ft tile): head h = col>>5 (F=32 aligned).
// Y2 may alias X (row-exclusive blocks).
__global__ __launch_bounds__(256) void gemm_dual(const void* __restrict__ X, int xext,
                                                 const unsigned short* __restrict__ WT1,
                                                 const unsigned short* __restrict__ WT2,
                                                 bf16* __restrict__ Y1, bf16* __restrict__ Y2,
                                                 int nrows, const float* __restrict__ ka,
                                                 const float* __restrict__ kb,
                                                 const void* __restrict__ al,
                                                 const void* __restrict__ ar,
                                                 float* __restrict__ elo,
                                                 float* __restrict__ ero,
                                                 const int* __restrict__ flag) {
    constexpr int LDX = 136;
    __shared__ unsigned short Xs[64 * LDX];   // [r][k]
    __shared__ unsigned short Wt[128 * LDX];  // [c][k], reused for W1 then W2
    int m = (*flag != 0) ? 1 : 0;
    int xfp32 = xext && m;
    int tid = threadIdx.x;
    int rb = blockIdx.x * 64;

    if (xfp32) {
#pragma unroll
        for (int it = 0; it < 8; it++) {  // float4 = 4 elems
            int e = (tid + it * 256) * 4;
            int r = e >> 7, k0 = e & 127;
            int row = rb + r;
            float4 v = {0.f, 0.f, 0.f, 0.f};
            if (row < nrows) v = *(const float4*)((const float*)X + (size_t)row * 128 + k0);
            unsigned lo = (unsigned)f2bfu(v.x) | ((unsigned)f2bfu(v.y) << 16);
            unsigned hi = (unsigned)f2bfu(v.z) | ((unsigned)f2bfu(v.w) << 16);
            uint2 o = {lo, hi};
            *(uint2*)&Xs[r * LDX + k0] = o;
        }
    } else {
#pragma unroll
        for (int it = 0; it < 4; it++) {  // uint4 = 8 bf16
            int e = (tid + it * 256) * 8;
            int r = e >> 7, k0 = e & 127;
            int row = rb + r;
            uint4 v = {0u, 0u, 0u, 0u};
            if (row < nrows) v = *(const uint4*)((const unsigned short*)X + (size_t)row * 128 + k0);
            if (ka) v = bnx8(v, k0, ka, kb);
            *(uint4*)&Xs[r * LDX + k0] = v;
        }
    }
#pragma unroll
    for (int it = 0; it < 8; it++) {  // 128x128 weight tile
        int e = (tid + it * 256) * 8;
        int c = e >> 7, k0 = e & 127;
        *(uint4*)&Wt[c * LDX + k0] = *(const uint4*)(WT1 + (size_t)c * 128 + k0);
    }
    __syncthreads();

    int wave = tid >> 6, lane = tid & 63;
    int lr = lane & 15, quad = lane >> 4;
    int mrow = wave * 16 + lr;
    int drow = rb + wave * 16 + quad * 4;

    {
        f32x4 acc[8] = {};
        for (int kk = 0; kk < 128; kk += 32) {
            bf16x8 a = *(const bf16x8*)&Xs[mrow * LDX + kk + quad * 8];
#pragma unroll
            for (int nt = 0; nt < 8; nt++) {
                bf16x8 b = *(const bf16x8*)&Wt[(nt * 16 + lr) * LDX + kk + quad * 8];
                acc[nt] = __builtin_amdgcn_mfma_f32_16x16x32_bf16(a, b, acc[nt], 0, 0, 0);
            }
        }
#pragma unroll
        for (int nt = 0; nt < 8; nt++) {
            int col = nt * 16 + lr;
#pragma unroll
            for (int i = 0; i < 4; i++) {
                int row = drow + i;
                if (row < nrows) Y1[(size_t)row * 128 + col] = __float2bfloat16(acc[nt][i]);
            }
        }
        // ---- fused el/er: el[row,h] = sum_col(head h) ft[row,col]*al_flat[col] ----
        float alv[8], arv[8];
#pragma unroll
        for (int nt = 0; nt < 8; nt++) {
            int c = nt * 16 + lr;
            alv[nt] = ldx(al, c, m);
            arv[nt] = ldx(ar, c, m);
        }
        float eo = 0.f, ro = 0.f;
#pragma unroll
        for (int i = 0; i < 4; i++) {
#pragma unroll
            for (int h = 0; h < 4; h++) {
                float es = acc[2 * h][i] * alv[2 * h] + acc[2 * h + 1][i] * alv[2 * h + 1];
                float rs = acc[2 * h][i] * arv[2 * h] + acc[2 * h + 1][i] * arv[2 * h + 1];
#pragma unroll
                for (int off = 1; off < 16; off <<= 1) {
                    es += __shfl_xor(es, off);
                    rs += __shfl_xor(rs, off);
                }
                bool mine = (lr == i * 4 + h);  // (i,h) -> lane: el idx = drow*4 + lr
                eo = mine ? es : eo;
                ro = mine ? rs : ro;
            }
        }
        int erow = drow + (lr >> 2);
        if (erow < nrows) {
            elo[(size_t)drow * 4 + lr] = eo;  // coalesced 64B per quad
            ero[(size_t)drow * 4 + lr] = ro;
        }
    }
    __syncthreads();  // all waves done reading W1 tile
#pragma unroll
    for (int it = 0; it < 8; it++) {
        int e = (tid + it * 256) * 8;
        int c = e >> 7, k0 = e & 127;
        *(uint4*)&Wt[c * LDX + k0] = *(const uint4*)(WT2 + (size_t)c * 128 + k0);
    }
    __syncthreads();
    {
        f32x4 acc[8] = {};
        for (int kk = 0; kk < 128; kk += 32) {
            bf16x8 a = *(const bf16x8*)&Xs[mrow * LDX + kk + quad * 8];
#pragma unroll
            for (int nt = 0; nt < 8; nt++) {
                bf16x8 b = *(const bf16x8*)&Wt[(nt * 16 + lr) * LDX + kk + quad * 8];
                acc[nt] = __builtin_amdgcn_mfma_f32_16x16x32_bf16(a, b, acc[nt], 0, 0, 0);
            }
        }
#pragma unroll
        for (int nt = 0; nt < 8; nt++) {
            int col = nt * 16 + lr;
#pragma unroll
            for (int i = 0; i < 4; i++) {
                int row = drow + i;
                if (row < nrows) Y2[(size_t)row * 128 + col] = __float2bfloat16(acc[nt][i]);
            }
        }
    }
}

// ---------------- layer-2 fused GEMM: stage BN(hbuf) once ----------------
// WT: [208][128]  rows 0..159 = w_fc2^T, rows 160..207 = wmt (zero-pad >=40)
// writes: Y[.,0:160] = X@w_fc2 ; X[.,0:40] = X@wmt^T (in-place, row-exclusive)
__global__ __launch_bounds__(256) void gemm_final(bf16* __restrict__ X,
                                                  const unsigned short* __restrict__ WT,
                                                  bf16* __restrict__ Y, int nrows,
                                                  const float* __restrict__ ka,
                                                  const float* __restrict__ kb) {
    constexpr int LDX = 136;
    __shared__ unsigned short Xs[64 * LDX];   // [r][k]
    __shared__ unsigned short Wt[128 * LDX];  // phase1: rows 0..127; phase2: rows 128..207
    int tid = threadIdx.x;
    int rb = blockIdx.x * 64;

#pragma unroll
    for (int it = 0; it < 4; it++) {
        int e = (tid + it * 256) * 8;
        int r = e >> 7, k0 = e & 127;
        int row = rb + r;
        uint4 v = {0u, 0u, 0u, 0u};
        if (row < nrows) v = *(const uint4*)((const unsigned short*)X + (size_t)row * 128 + k0);
        v = bnx8(v, k0, ka, kb);
        *(uint4*)&Xs[r * LDX + k0] = v;
    }
#pragma unroll
    for (int it = 0; it < 8; it++) {
        int e = (tid + it * 256) * 8;
        int c = e >> 7, k0 = e & 127;
        *(uint4*)&Wt[c * LDX + k0] = *(const uint4*)(WT + (size_t)c * 128 + k0);
    }
    __syncthreads();

    int wave = tid >> 6, lane = tid & 63;
    int lr = lane & 15, quad = lane >> 4;
    int mrow = wave * 16 + lr;
    int drow = rb + wave * 16 + quad * 4;

    {  // phase 1: output cols 0..127
        f32x4 acc[8] = {};
        for (int kk = 0; kk < 128; kk += 32) {
            bf16x8 a = *(const bf16x8*)&Xs[mrow * LDX + kk + quad * 8];
#pragma unroll
            for (int nt = 0; nt < 8; nt++) {
                bf16x8 b = *(const bf16x8*)&Wt[(nt * 16 + lr) * LDX + kk + quad * 8];
                acc[nt] = __builtin_amdgcn_mfma_f32_16x16x32_bf16(a, b, acc[nt], 0, 0, 0);
            }
        }
#pragma unroll
        for (int nt = 0; nt < 8; nt++) {
            int col = nt * 16 + lr;
#pragma unroll
            for (int i = 0; i < 4; i++) {
                int row = drow + i;
                if (row < nrows) Y[(size_t)row * 160 + col] = __float2bfloat16(acc[nt][i]);
            }
        }
    }
    __syncthreads();
#pragma unroll
    for (int it = 0; it < 5; it++) {  // 80 rows (128..207)
        int e = (tid + it * 256) * 8;
        int c = e >> 7, k0 = e & 127;
        *(uint4*)&Wt[c * LDX + k0] = *(const uint4*)(WT + (size_t)(128 + c) * 128 + k0);
    }
    __syncthreads();
    {  // phase 2: output cols 128..159 (->Y) and skipmean cols 0..39 (->X)
        f32x4 acc[5] = {};
        for (int kk = 0; kk < 128; kk += 32) {
            bf16x8 a = *(const bf16x8*)&Xs[mrow * LDX + kk + quad * 8];
#pragma unroll
            for (int nt = 0; nt < 5; nt++) {
                bf16x8 b = *(const bf16x8*)&Wt[(nt * 16 + lr) * LDX + kk + quad * 8];
                acc[nt] = __builtin_amdgcn_mfma_f32_16x16x32_bf16(a, b, acc[nt], 0, 0, 0);
            }
        }
#pragma unroll
        for (int nt = 0; nt < 5; nt++) {
            int colg = 128 + nt * 16 + lr;
#pragma unroll
            for (int i = 0; i < 4; i++) {
                int row = drow + i;
                if (row >= nrows) continue;
                if (colg < 160) {
                    Y[(size_t)row * 160 + colg] = __float2bfloat16(acc[nt][i]);
                } else {
                    int sc = colg - 160;
                    if (sc < 40) X[(size_t)row * 128 + sc] = __float2bfloat16(acc[nt][i]);
                }
            }
        }
    }
}

// ---------------- el/er: [N,H] dot over F (layer 2 only, F=40) ----------------
__global__ void elr_kernel(const bf16* __restrict__ ft, const void* __restrict__ al,
                           const void* __restrict__ ar, float* __restrict__ el,
                           float* __restrict__ er, int n, int F, const int* __restrict__ flag) {
    int m = (*flag != 0) ? 1 : 0;
    int gid = blockIdx.x * blockDim.x + threadIdx.x;
    if (gid >= n * 4) return;
    int nid = gid >> 2, h = gid & 3;
    const bf16* f = ft + (size_t)nid * (4 * F) + h * F;
    float sl = 0.f, sr = 0.f;
    for (int i0 = 0; i0 < F; i0 += 8) {
        bf16x8 v8 = *(const bf16x8*)(f + i0);
#pragma unroll
        for (int i = 0; i < 8; i++) {
            float v = __uint_as_float(((unsigned)(unsigned short)v8[i]) << 16);
            sl += v * ldx(al, h * F + i0 + i, m);
            sr += v * ldx(ar, h * F + i0 + i, m);
        }
    }
    el[gid] = sl;
    er[gid] = sr;
}

// ---------------- per-dst softmax + aggregation: ONE WAVE PER NODE, zero barriers ----------------
// Gather: batches of 8 edges; u broadcast via readlane (SGPR base), 8 loads in flight.
template <int FTOT, bool FINAL>
__global__ __launch_bounds__(256) void agg_wave(
    const bf16* __restrict__ ft, const float* __restrict__ el, const float* __restrict__ er,
    const int* __restrict__ indptr, const int* __restrict__ csr_src,
    const void* __restrict__ bias, const void* __restrict__ h_in,
    const bf16* __restrict__ skip_pre, bf16* __restrict__ out,
    const void* __restrict__ bias_last, void* __restrict__ fout,
    const int* __restrict__ flag) {
    constexpr int HF = FTOT / 4;
    int m = (*flag != 0) ? 1 : 0;
    int lane = threadIdx.x & 63;
    int v = blockIdx.x * 4 + (threadIdx.x >> 6);
    if (v >= GN) return;
    int beg = indptr[v], end = indptr[v + 1];
    beg = max(0, min(beg, GE));
    end = max(beg, min(end, GE));

    int h = lane & 3, jl = lane >> 2;  // weight-phase mapping: edge slot jl, head h
    int c0 = 2 * lane;                 // gather-phase feature pair
    int h0 = c0 / HF;
    float erv = er[v * 4 + h];

    float a0 = 0.f, a1 = 0.f, a2 = 0.f, a3 = 0.f;
    float s_part = 0.f;

    for (int cb = beg; cb < end; cb += 16) {
        int chn = end - cb;
        chn = chn < 16 ? chn : 16;
        // ---- weight phase (this chunk's 16 edges) ----
        int u = csr_src[cb + (jl < chn ? jl : chn - 1)];
        u = min(max(u, 0), GN - 1);
        float e = el[u * 4 + h] + erv;
        e = e > 0.f ? e : 0.2f * e;
        float w = (jl < chn) ? __expf(fminf(e, 60.f)) : 0.f;
        s_part += w;
        // ---- gather phase: batches of 8 edges; all loads independent, issued together ----
#pragma unroll
        for (int jb = 0; jb < 16; jb += 8) {
            if (jb >= chn) break;  // wave-uniform
            unsigned pq[8];
            float wqv[8];
            unsigned pbq[8];
#pragma unroll
            for (int q = 0; q < 8; q++) {
                int j4 = (jb + q) * 4;
                int us = __builtin_amdgcn_readlane(u, j4);  // SGPR base, no LDS-pipe dep
                pq[q] = *(const unsigned*)(ft + (size_t)us * FTOT + c0);
                wqv[q] = __shfl(w, j4 + h0);
                if constexpr (FINAL) {
                    if (lane < 16) {
                        pbq[q] = *(const unsigned*)(ft + (size_t)us * FTOT + 128 + c0);
                    }
                }
            }
#pragma unroll
            for (int q = 0; q < 8; q++) {
                a0 += wqv[q] * lo16(pq[q]);
                a1 += wqv[q] * hi16(pq[q]);
                if constexpr (FINAL) {
                    // pair1 cols 128..159 are head 3: uniform weight via readlane
                    float wb = __uint_as_float(
                        __builtin_amdgcn_readlane(__float_as_uint(w), (jb + q) * 4 + 3));
                    if (lane < 16) {
                        a2 += wb * lo16(pbq[q]);
                        a3 += wb * hi16(pbq[q]);
                    }
                }
            }
        }
    }

    // ---- s reduction: butterfly over slot bits (head preserved in lane&3) ----
#pragma unroll
    for (int off = 4; off < 64; off <<= 1) s_part += __shfl_xor(s_part, off);
    float s0 = __shfl(s_part, h0);  // lane h0 (0..3) holds head-h0 total

    float r0 = (s0 > 0.f) ? a0 / s0 : 0.f;
    float r1 = (s0 > 0.f) ? a1 / s0 : 0.f;

    if constexpr (!FINAL) {
        unsigned pk = *(const unsigned*)(skip_pre + (size_t)v * FTOT + c0);
        float o0 = r0 + ldx(bias, c0, m) + lo16(pk);
        float o1 = r1 + ldx(bias, c0 + 1, m) + hi16(pk);
        unsigned po = ((unsigned)f2bfu(guard_finite(o1)) << 16) |
                      (unsigned)f2bfu(guard_finite(o0));
        *(unsigned*)(out + (size_t)v * FTOT + c0) = po;
    } else {
        float s3 = __shfl(s_part, 3);
        float o0 = r0 + ldx(bias, c0, m);
        float o1 = r1 + ldx(bias, c0 + 1, m);
        float r2 = (s3 > 0.f) ? a2 / s3 : 0.f;
        float r3 = (s3 > 0.f) ? a3 / s3 : 0.f;
        int cb0 = 128 + c0;  // meaningful for lane<16 only
        float o2 = r2 + ldx(bias, (cb0 < FTOT) ? cb0 : 0, m);
        float o3 = r3 + ldx(bias, (cb0 + 1 < FTOT) ? cb0 + 1 : 1, m);

        // head-average: lane t<40 needs cols t, t+40, t+80, t+120 (all parity t&1)
        int t = lane;
        bool od = (t & 1);
        int sA = (t >> 1) & 63;
        int sB = ((t + 40) >> 1) & 63;
        int sC = ((t + 80) >> 1) & 63;
        int sD1 = ((t + 120) >> 1) & 63;          // valid when t<8 (col<128, from o0/o1)
        int sD2 = ((t >= 8 ? t - 8 : 0) >> 1);    // valid when t>=8 (col>=128, from o2/o3)
        float vA0 = __shfl(o0, sA), vA1 = __shfl(o1, sA);
        float vB0 = __shfl(o0, sB), vB1 = __shfl(o1, sB);
        float vC0 = __shfl(o0, sC), vC1 = __shfl(o1, sC);
        float vD10 = __shfl(o0, sD1), vD11 = __shfl(o1, sD1);
        float vD20 = __shfl(o2, sD2), vD21 = __shfl(o3, sD2);
        float vA = od ? vA1 : vA0;
        float vB = od ? vB1 : vB0;
        float vC = od ? vC1 : vC0;
        float vD = (t < 8) ? (od ? vD11 : vD10) : (od ? vD21 : vD20);

        float x = -3.0e38f;
        if (t < 40) {
            float sm = __bfloat162float(((const bf16*)h_in)[(size_t)v * 128 + t]);
            x = 0.25f * (vA + vB + vC + vD) + sm + ldx(bias_last, t, m);
        }
        float mx = x;
#pragma unroll
        for (int off = 1; off < 64; off <<= 1) mx = fmaxf(mx, __shfl_xor(mx, off));
        float ex = (t < 40) ? __expf(x - mx) : 0.f;
        float sum = ex;
#pragma unroll
        for (int off = 1; off < 64; off <<= 1) sum += __shfl_xor(sum, off);
        if (t < 40) stx(fout, (size_t)v * 40 + t, m, guard_finite(x - mx - __logf(sum)));
    }
}

// ---------------- BatchNorm stats on bf16 [N,128]: vectorized + LDS reduce ----------------
__global__ void bn_stats(const bf16* __restrict__ x, float* __restrict__ gsum,
                         float* __restrict__ gsq, int n) {
    __shared__ float ls[128], lq[128];
    int tid = threadIdx.x;  // 256
    if (tid < 128) {
        ls[tid] = 0.f;
        lq[tid] = 0.f;
    }
    __syncthreads();
    int rg = tid >> 4;         // 0..15 row substream
    int c8 = (tid & 15) * 8;   // col start
    int rows_per_block = (n + gridDim.x - 1) / gridDim.x;
    int r0 = blockIdx.x * rows_per_block;
    int r1 = min(n, r0 + rows_per_block);
    float s[8] = {}, q[8] = {};
    for (int r = r0 + rg; r < r1; r += 16) {
        uint4 v = *(const uint4*)((const unsigned short*)x + (size_t)r * 128 + c8);
        unsigned* pw = (unsigned*)&v;
#pragma unroll
        for (int i = 0; i < 4; i++) {
            float v0 = lo16(pw[i]), v1 = hi16(pw[i]);
            s[2 * i] += v0;
            q[2 * i] += v0 * v0;
            s[2 * i + 1] += v1;
            q[2 * i + 1] += v1 * v1;
        }
    }
#pragma unroll
    for (int i = 0; i < 8; i++) {
        atomicAdd(&ls[c8 + i], s[i]);
        atomicAdd(&lq[c8 + i], q[i]);
    }
    __syncthreads();
    if (tid < 128) {
        atomicAdd(&gsum[tid], ls[tid]);
        atomicAdd(&gsq[tid], lq[tid]);
    }
}

extern "C" void kernel_launch(void* const* d_in, const int* in_sizes, int n_in,
                              void* d_out, int out_size, void* d_ws, size_t ws_size,
                              hipStream_t stream) {
    const void* feat = d_in[0];
    const int* src = (const int*)d_in[1];
    const int* dst = (const int*)d_in[2];
    const void* w_fc0 = d_in[3];
    const void* al0 = d_in[4];
    const void* ar0 = d_in[5];
    const void* b0 = d_in[6];
    const void* w_lin0 = d_in[7];
    const void* g0 = d_in[8];
    const void* be0 = d_in[9];
    const void* w_fc1 = d_in[10];
    const void* al1 = d_in[11];
    const void* ar1 = d_in[12];
    const void* b1 = d_in[13];
    const void* w_lin1 = d_in[14];
    const void* g1 = d_in[15];
    const void* be1 = d_in[16];
    const void* w_fc2 = d_in[17];
    const void* al2 = d_in[18];
    const void* ar2 = d_in[19];
    const void* b2 = d_in[20];
    const void* w_lin2 = d_in[21];
    const void* bias_last = d_in[22];

    // ---- workspace guard: total need ~34.6 MB ----
    if (ws_size < 35000000) {
        sentinel_kernel<<<(out_size + 255) / 256, 256, 0, stream>>>((unsigned short*)d_out,
                                                                    out_size);
        return;
    }

    char* p = (char*)d_ws;
    auto alloc = [&](size_t bytes) {
        char* r = p;
        p += (bytes + 255) & ~(size_t)255;
        return r;
    };
    bf16* ftb = (bf16*)alloc((size_t)GN * 160 * 2);   // 16.0 MB
    bf16* hbuf = (bf16*)alloc((size_t)GN * 128 * 2);  // 12.8 MB
    float* elb = (float*)alloc((size_t)GN * 4 * 4);   // 0.8 MB
    float* erb = (float*)alloc((size_t)GN * 4 * 4);   // 0.8 MB
    int* indptr = (int*)alloc((size_t)(GN + 1) * 4);
    int* cursor = (int*)alloc((size_t)GN * 4);
    int* bsum = (int*)alloc(256 * 4);                 // block sums for 3-pass scan
    unsigned short* wtf0 = (unsigned short*)alloc(128 * 128 * 2);  // pre-transposed weights
    unsigned short* wtl0 = (unsigned short*)alloc(128 * 128 * 2);
    unsigned short* wtf1 = (unsigned short*)alloc(128 * 128 * 2);
    unsigned short* wtl1 = (unsigned short*)alloc(128 * 128 * 2);
    unsigned short* wtf2 = (unsigned short*)alloc(208 * 128 * 2);  // rows 160..207 = wmt
    float* ka0 = (float*)alloc(128 * 4);
    float* kb0 = (float*)alloc(128 * 4);
    float* ka1 = (float*)alloc(128 * 4);
    float* kb1 = (float*)alloc(128 * 4);
    char* zbase = p;  // ---- zero-initialized region ----
    int* deg = (int*)alloc((size_t)GN * 4);
    int* csr = (int*)alloc((size_t)GE * 4);  // 3.2 MB
    float* gs0 = (float*)alloc(128 * 4);
    float* gq0 = (float*)alloc(128 * 4);
    float* gs1 = (float*)alloc(128 * 4);
    float* gq1 = (float*)alloc(128 * 4);
    int* flag = (int*)alloc(4);
    hipMemsetAsync(zbase, 0, (size_t)(p - zbase), stream);

    unsigned short* wmt = wtf2 + 160 * 128;  // wmean rows appended to WT2

    detect_kernel<<<1, 256, 0, stream>>>((const unsigned short*)feat, flag);

    // CSR build + weight precompute (independent, early)
    const int NB = (GN + 255) / 256;  // 196 scan blocks
    count_kernel<<<(GE + 255) / 256, 256, 0, stream>>>(dst, deg, GE);
    scan1_kernel<<<NB, 256, 0, stream>>>(deg, cursor, bsum, GN);   // cursor = per-block incl scan
    scan2_kernel<<<1, 256, 0, stream>>>(bsum, NB);                 // bsum = exclusive block offs
    scan3_kernel<<<NB, 256, 0, stream>>>(deg, cursor, bsum, indptr, cursor, GN);
    scatter_kernel<<<(GE + 255) / 256, 256, 0, stream>>>(src, dst, cursor, csr, GE);
    wmean_kernel<<<24, 256, 0, stream>>>(w_lin2, wmt, flag);
    wtrans_all<<<(4 * 16384 + 160 * 128 + 255) / 256, 256, 0, stream>>>(
        w_fc0, w_lin0, w_fc1, w_lin1, w_fc2, wtf0, wtl0, wtf1, wtl1, wtf2, flag);

    const int AGGB = (GN + 3) / 4;  // 12500 blocks, 4 waves (nodes) each

    // ----- Layer 0 (fused: ftb = feat@w_fc0, hbuf = feat@w_lin0, el/er epilogue) -----
    gemm_dual<<<782, 256, 0, stream>>>(feat, 1, wtf0, wtl0, ftb, hbuf, GN, nullptr, nullptr,
                                       al0, ar0, elb, erb, flag);
    agg_wave<128, false><<<AGGB, 256, 0, stream>>>(ftb, elb, erb, indptr, csr, b0, nullptr,
                                                   hbuf, hbuf, nullptr, nullptr, flag);
    bn_stats<<<256, 256, 0, stream>>>(hbuf, gs0, gq0, GN);
    bn_coef<<<1, 128, 0, stream>>>(gs0, gq0, g0, be0, ka0, kb0, GN, flag);

    // ----- Layer 1 (fused: BN0+ReLU staging; ftb = h1@w_fc1, hbuf <- h1@w_lin1, el/er) -----
    gemm_dual<<<782, 256, 0, stream>>>(hbuf, 0, wtf1, wtl1, ftb, hbuf, GN, ka0, kb0,
                                       al1, ar1, elb, erb, flag);
    agg_wave<128, false><<<AGGB, 256, 0, stream>>>(ftb, elb, erb, indptr, csr, b1, nullptr,
                                                   hbuf, hbuf, nullptr, nullptr, flag);
    bn_stats<<<256, 256, 0, stream>>>(hbuf, gs1, gq1, GN);
    bn_coef<<<1, 128, 0, stream>>>(gs1, gq1, g1, be1, ka1, kb1, GN, flag);

    // ----- Layer 2 (fused: BN1+ReLU staging; ftb = h2@w_fc2 [160 cols]; hbuf[:,0:40] = skipmean) -----
    gemm_final<<<782, 256, 0, stream>>>(hbuf, wtf2, ftb, GN, ka1, kb1);
    elr_kernel<<<(GN * 4 + 255) / 256, 256, 0, stream>>>(ftb, al2, ar2, elb, erb, GN, 40, flag);
    agg_wave<160, true><<<AGGB, 256, 0, stream>>>(ftb, elb, erb, indptr, csr, b2, hbuf,
                                                  nullptr, nullptr, bias_last, d_out, flag);
}